// Round 1
// baseline (8931.171 us; speedup 1.0000x reference)
//
#include <hip/hip_runtime.h>

#define K_B    32
#define K_CXC  3
#define K_XS   64
#define K_CY   32
#define K_KS   10
#define K_M    55
#define K_Z    256
#define K_P    (K_M*K_M)          // 3025
#define K_FEAT (K_CY*K_P)         // 96800
#define K_XN   (K_CXC*K_XS*K_XS)  // 12288 per batch

// ---------------------------------------------------------------- prep: kernel transposes
// KwT1[((cx*10+ky)*10+kx)*32 + cy] = Kw[cy][cx][ky][kx]           (for conv_fwd)
// KwT2[((cy*10+ky)*10+kx)*4 + cx]  = Kw[cy][cx][9-ky][9-kx]       (flipped, for convT)
__global__ __launch_bounds__(256) void prep_kw(const float* __restrict__ Kw,
                                               float* __restrict__ KwT1,
                                               float* __restrict__ KwT2) {
    int idx = blockIdx.x*256 + threadIdx.x;
    if (idx < 9600) {
        int cy = idx & 31, s = idx >> 5;           // s = cx*100+ky*10+kx
        KwT1[idx] = Kw[cy*300 + s];
    } else if (idx < 9600 + 12800) {
        int o = idx - 9600;
        int c = o & 3, s = o >> 2;                 // s = cy*100+ky*10+kx
        int kx = s % 10, ky = (s/10) % 10, cy = s/100;
        KwT2[o] = (c < 3) ? Kw[cy*300 + c*100 + (9-ky)*10 + (9-kx)] : 0.0f;
    }
}

// ---------------------------------------------------------------- channel softmax (32 ch, stride 3025)
__global__ __launch_bounds__(256) void softmax_ch(const float* __restrict__ in,
                                                  float* __restrict__ out, float beta) {
    int tid = blockIdx.x*256 + threadIdx.x;
    if (tid >= K_B*K_P) return;
    int b = tid / K_P, p = tid - b*K_P;
    const float* ip = in + b*K_FEAT + p;
    float v[32];
    #pragma unroll
    for (int c = 0; c < 32; ++c) v[c] = ip[c*K_P];
    float m = v[0];
    #pragma unroll
    for (int c = 1; c < 32; ++c) m = fmaxf(m, v[c]);
    float s = 0.f;
    #pragma unroll
    for (int c = 0; c < 32; ++c) { v[c] = __expf(beta*(v[c]-m)); s += v[c]; }
    float inv = 1.0f / s;
    float* op = out + b*K_FEAT + p;
    #pragma unroll
    for (int c = 0; c < 32; ++c) op[c*K_P] = v[c]*inv;
}

// ---------------------------------------------------------------- GEMM1: z[b][zi] += sum_k W[zi][k]*fy[b][k]
// grid (16 row-blocks, 32 k-splits), 256 thr. thread=(r=t&15, kl=t>>4).
// W float4 in regs (coalesced); fy chunk [32][64] in LDS, b128 broadcast reads.
__global__ __launch_bounds__(256) void gemm1(const float* __restrict__ W,
                                             const float* __restrict__ fy,
                                             float* __restrict__ z) {
    __shared__ __align__(16) float sm[8192];      // fy chunk (2048) / reduce (8192)
    int t = threadIdx.x;
    int r = t & 15, kl = t >> 4;
    int zi0 = blockIdx.x * 16;
    int kstart = blockIdx.y * 3040;
    int kend = min(kstart + 3040, K_FEAT);
    int nch = (kend - kstart + 63) >> 6;
    float acc[32];
    #pragma unroll
    for (int b = 0; b < 32; ++b) acc[b] = 0.f;
    int sb = t >> 3, sj = t & 7;
    const float* Wrow = W + (zi0 + r)*K_FEAT;
    const float* fyrow = fy + sb*K_FEAT;
    for (int c = 0; c < nch; ++c) {
        int kbase = kstart + c*64;
        int kk0 = kbase + sj*8;
        float4 f0, f1;
        if (kk0 + 8 <= kend) {
            f0 = *(const float4*)(fyrow + kk0);
            f1 = *(const float4*)(fyrow + kk0 + 4);
        } else {
            float tmp[8];
            #pragma unroll
            for (int i = 0; i < 8; ++i) tmp[i] = (kk0 + i < kend) ? fyrow[kk0+i] : 0.f;
            f0 = make_float4(tmp[0],tmp[1],tmp[2],tmp[3]);
            f1 = make_float4(tmp[4],tmp[5],tmp[6],tmp[7]);
        }
        int kw = kbase + kl*4;
        float4 w;
        if (kw + 4 <= kend) {
            w = *(const float4*)(Wrow + kw);
        } else {
            float tmp[4];
            #pragma unroll
            for (int i = 0; i < 4; ++i) tmp[i] = (kw + i < kend) ? Wrow[kw+i] : 0.f;
            w = make_float4(tmp[0],tmp[1],tmp[2],tmp[3]);
        }
        __syncthreads();                            // prior chunk reads done
        *(float4*)&sm[sb*64 + sj*8]     = f0;
        *(float4*)&sm[sb*64 + sj*8 + 4] = f1;
        __syncthreads();
        #pragma unroll
        for (int b = 0; b < 32; ++b) {
            float4 f = *(const float4*)&sm[b*64 + kl*4];
            acc[b] += w.x*f.x + w.y*f.y + w.z*f.z + w.w*f.w;
        }
    }
    __syncthreads();
    #pragma unroll
    for (int b = 0; b < 32; ++b) sm[(kl*16 + r)*32 + b] = acc[b];
    __syncthreads();
    for (int q = t; q < 512; q += 256) {
        int rr = q >> 5, bb = q & 31;
        float s = 0.f;
        #pragma unroll
        for (int kk = 0; kk < 16; ++kk) s += sm[(kk*16 + rr)*32 + bb];
        atomicAdd(&z[bb*K_Z + zi0 + rr], s);
    }
}

// ---------------------------------------------------------------- softmax over z slots (256), write fzT[z][b]
__global__ __launch_bounds__(256) void softmax_fz(const float* __restrict__ z,
                                                  float* __restrict__ fzT) {
    __shared__ float sr[256];
    int b = blockIdx.x, t = threadIdx.x;
    float v = 7.0f * z[b*K_Z + t];
    sr[t] = v; __syncthreads();
    for (int off = 128; off > 0; off >>= 1) {
        if (t < off) sr[t] = fmaxf(sr[t], sr[t+off]);
        __syncthreads();
    }
    float m = sr[0];
    __syncthreads();
    float e = __expf(v - m);
    sr[t] = e; __syncthreads();
    for (int off = 128; off > 0; off >>= 1) {
        if (t < off) sr[t] += sr[t+off];
        __syncthreads();
    }
    float s = sr[0];
    fzT[t*32 + b] = e / s;
}

// ---------------------------------------------------------------- GEMM2 + y update:
// top[b][f] = sum_z W[z][f]*fz[b][z];  y = 0.5*(y + conv_x + top)
__global__ __launch_bounds__(256) void gemm2(const float* __restrict__ W,
                                             const float* __restrict__ fzT,
                                             const float* __restrict__ cxb,
                                             float* __restrict__ y) {
    int f = blockIdx.x*256 + threadIdx.x;
    if (f >= K_FEAT) return;
    float acc[32];
    #pragma unroll
    for (int b = 0; b < 32; ++b) acc[b] = 0.f;
    const float* wp = W + f;
    #pragma unroll 2
    for (int zz = 0; zz < K_Z; ++zz) {
        float w = wp[zz*K_FEAT];
        const float* fzp = fzT + zz*32;             // uniform -> scalar loads
        #pragma unroll
        for (int b = 0; b < 32; ++b) acc[b] = fmaf(w, fzp[b], acc[b]);
    }
    #pragma unroll
    for (int b = 0; b < 32; ++b) {
        int idx = b*K_FEAT + f;
        y[idx] = 0.5f*(y[idx] + cxb[idx] + acc[b]);
    }
}

// ---------------------------------------------------------------- forward conv: cx[b][cy][55][55]
// grid (49 tiles, 32 b), 256 thr = 64 pix * 4 cy-groups, 8 cy accs each
__global__ __launch_bounds__(256) void conv_fwd(const float* __restrict__ x,
                                                const float* __restrict__ KwT1,
                                                float* __restrict__ out) {
    __shared__ __align__(16) float kws[9600];
    __shared__ float xs[1020];                      // [3][17][20]
    int t = threadIdx.x;
    int b = blockIdx.y;
    int tile = blockIdx.x;
    int ty0 = (tile/7)*8, tx0 = (tile%7)*8;
    for (int i = t; i < 9600; i += 256) kws[i] = KwT1[i];
    for (int i = t; i < 1020; i += 256) {
        int cxi = i/340, rem = i - cxi*340, rr = rem/20, cc = rem - rr*20;
        float v = 0.f;
        int row = ty0+rr, col = tx0+cc;
        if (cc < 17 && row < 64 && col < 64) v = x[b*K_XN + cxi*4096 + row*64 + col];
        xs[i] = v;
    }
    __syncthreads();
    int pix = t & 63, px = pix & 7, py = pix >> 3;
    int cy0 = (t >> 6) * 8;
    float acc[8];
    #pragma unroll
    for (int i = 0; i < 8; ++i) acc[i] = 0.f;
    for (int cxi = 0; cxi < 3; ++cxi)
      for (int ky = 0; ky < 10; ++ky) {
        const float* xr = &xs[cxi*340 + (py+ky)*20 + px];
        const float* kr = &kws[(cxi*100 + ky*10)*32 + cy0];
        #pragma unroll
        for (int kx = 0; kx < 10; ++kx) {
            float xv = xr[kx];
            float4 a  = *(const float4*)(kr + kx*32);
            float4 b4 = *(const float4*)(kr + kx*32 + 4);
            acc[0] += xv*a.x;  acc[1] += xv*a.y;  acc[2] += xv*a.z;  acc[3] += xv*a.w;
            acc[4] += xv*b4.x; acc[5] += xv*b4.y; acc[6] += xv*b4.z; acc[7] += xv*b4.w;
        }
      }
    int oy = ty0+py, ox = tx0+px;
    if (oy < 55 && ox < 55) {
        int base = b*K_FEAT + cy0*K_P + oy*55 + ox;
        #pragma unroll
        for (int i = 0; i < 8; ++i) out[base + i*K_P] = acc[i];
    }
}

// ---------------------------------------------------------------- x *= 0.9 (exact grid)
__global__ __launch_bounds__(256) void x_scale(float* __restrict__ x) {
    int i = blockIdx.x*256 + threadIdx.x;
    x[i] *= 0.9f;
}

// ---------------------------------------------------------------- adjoint conv, atomic += 0.1*x_inst
// grid (4 tiles 32x32, 4 cy-groups, 32 b), 256 thr = 32 px * 8 row-groups(4 rows)
__global__ __launch_bounds__(256) void convT(const float* __restrict__ sy,
                                             const float* __restrict__ KwT2,
                                             float* __restrict__ x) {
    __shared__ __align__(16) float kws[3200];       // [8cy][10][10][4]
    __shared__ float sys[14432];                    // [8cy][41][44]
    int t = threadIdx.x;
    int tile = blockIdx.x;
    int ti0 = (tile >> 1)*32, tj0 = (tile & 1)*32;
    int cy0 = blockIdx.y * 8;
    int b = blockIdx.z;
    for (int i = t; i < 3200; i += 256) kws[i] = KwT2[cy0*400 + i];
    for (int i = t; i < 14432; i += 256) {
        int cyi = i / 1804, rem = i - cyi*1804, rr = rem/44, cc = rem - rr*44;
        if (cc < 41) {
            int row = ti0 + rr - 9, col = tj0 + cc - 9;
            float v = (row >= 0 && row < 55 && col >= 0 && col < 55)
                        ? sy[b*K_FEAT + (cy0+cyi)*K_P + row*55 + col] : 0.f;
            sys[i] = v;
        }
    }
    __syncthreads();
    int px = t & 31, py0 = (t >> 5)*4;
    float acc[12];
    #pragma unroll
    for (int i = 0; i < 12; ++i) acc[i] = 0.f;
    for (int cyi = 0; cyi < 8; ++cyi) {
        for (int kx = 0; kx < 10; ++kx) {
            float4 kw[10];
            #pragma unroll
            for (int ky = 0; ky < 10; ++ky) kw[ky] = *(const float4*)&kws[((cyi*10+ky)*10 + kx)*4];
            const float* sp = &sys[cyi*1804 + px + kx];
            #pragma unroll
            for (int rr = 0; rr < 13; ++rr) {
                float sv = sp[(py0 + rr)*44];
                #pragma unroll
                for (int i = 0; i < 4; ++i) {
                    int ky = rr - i;
                    if (ky >= 0 && ky < 10) {
                        acc[i*3+0] += sv*kw[ky].x;
                        acc[i*3+1] += sv*kw[ky].y;
                        acc[i*3+2] += sv*kw[ky].z;
                    }
                }
            }
        }
    }
    int gb = b*K_XN;
    #pragma unroll
    for (int i = 0; i < 4; ++i) {
        int row = ti0 + py0 + i, col = tj0 + px;
        #pragma unroll
        for (int c = 0; c < 3; ++c)
            atomicAdd(&x[gb + c*4096 + row*64 + col], 0.1f*acc[i*3+c]);
    }
}

// ----------------------------------------------------------------
extern "C" void kernel_launch(void* const* d_in, const int* in_sizes, int n_in,
                              void* d_out, int out_size, void* d_ws, size_t ws_size,
                              hipStream_t stream) {
    const float* xin = (const float*)d_in[0];   // [32,3,64,64]
    const float* Kw  = (const float*)d_in[1];   // [32,3,10,10]
    const float* W   = (const float*)d_in[2];   // [256,96800]
    float* x = (float*)d_out;                   // x state lives in d_out

    float* ws   = (float*)d_ws;
    float* y    = ws;                           // 3,097,600
    float* fs   = y   + 3097600;                // fy / sy (disjoint lifetimes)
    float* cxb  = fs  + 3097600;                // conv_x
    float* z    = cxb + 3097600;                // 8192
    float* fzT  = z   + 8192;                   // 8192
    float* KwT1 = fzT + 8192;                   // 9600
    float* KwT2 = KwT1 + 9600;                  // 12800

    hipMemcpyAsync(x, xin, (size_t)K_B*K_XN*sizeof(float), hipMemcpyDeviceToDevice, stream);
    hipMemsetAsync(y, 0, (size_t)3097600*sizeof(float), stream);
    prep_kw<<<88, 256, 0, stream>>>(Kw, KwT1, KwT2);

    for (int s = 0; s < 30; ++s) {
        conv_fwd<<<dim3(49,32), 256, 0, stream>>>(x, KwT1, cxb);
        x_scale<<<1536, 256, 0, stream>>>(x);
        softmax_ch<<<379, 256, 0, stream>>>(y, fs, 3.0f);
        hipMemsetAsync(z, 0, 8192*sizeof(float), stream);
        gemm1<<<dim3(16,32), 256, 0, stream>>>(W, fs, z);
        softmax_fz<<<32, 256, 0, stream>>>(z, fzT);
        gemm2<<<379, 256, 0, stream>>>(W, fzT, cxb, y);
        softmax_ch<<<379, 256, 0, stream>>>(y, fs, 1.0f);
        convT<<<dim3(4,4,32), 256, 0, stream>>>(fs, KwT2, x);
    }
}

// Round 2
// 5855.857 us; speedup vs baseline: 1.5252x; 1.5252x over previous
//
#include <hip/hip_runtime.h>

#define K_B    32
#define K_CXC  3
#define K_XS   64
#define K_CY   32
#define K_KS   10
#define K_M    55
#define K_Z    256
#define K_P    (K_M*K_M)          // 3025
#define K_FEAT (K_CY*K_P)         // 96800
#define K_XN   (K_CXC*K_XS*K_XS)  // 12288 per batch

typedef __attribute__((ext_vector_type(8))) short short8;
typedef __attribute__((ext_vector_type(4))) float f32x4;

__device__ __forceinline__ short f2bf(float f) {
    unsigned u = __builtin_bit_cast(unsigned, f);
    unsigned r = (u + 0x7FFFu + ((u >> 16) & 1u)) >> 16;
    return (short)r;
}

// ---------------------------------------------------------------- W fp32 -> bf16 (once per launch)
__global__ __launch_bounds__(256) void w_to_bf16(const float* __restrict__ W,
                                                 short* __restrict__ Wb) {
    size_t i = ((size_t)blockIdx.x*256 + threadIdx.x) * 8;   // 24,780,800 total
    float4 a = *(const float4*)(W + i);
    float4 b = *(const float4*)(W + i + 4);
    short8 o;
    o[0]=f2bf(a.x); o[1]=f2bf(a.y); o[2]=f2bf(a.z); o[3]=f2bf(a.w);
    o[4]=f2bf(b.x); o[5]=f2bf(b.y); o[6]=f2bf(b.z); o[7]=f2bf(b.w);
    *(short8*)(Wb + i) = o;
}

// ---------------------------------------------------------------- kernel transposes
__global__ __launch_bounds__(256) void prep_kw(const float* __restrict__ Kw,
                                               float* __restrict__ KwT1,
                                               float* __restrict__ KwT2) {
    int idx = blockIdx.x*256 + threadIdx.x;
    if (idx < 9600) {
        int cy = idx & 31, s = idx >> 5;
        KwT1[idx] = Kw[cy*300 + s];
    } else if (idx < 9600 + 12800) {
        int o = idx - 9600;
        int c = o & 3, s = o >> 2;
        int kx = s % 10, ky = (s/10) % 10, cy = s/100;
        KwT2[o] = (c < 3) ? Kw[cy*300 + c*100 + (9-ky)*10 + (9-kx)] : 0.0f;
    }
}

// ---------------------------------------------------------------- channel softmax -> bf16 out (for gemm1 B)
__global__ __launch_bounds__(256) void softmax_ch_bf(const float* __restrict__ in,
                                                     short* __restrict__ out, float beta) {
    int tid = blockIdx.x*256 + threadIdx.x;
    if (tid >= K_B*K_P) return;
    int b = tid / K_P, p = tid - b*K_P;
    const float* ip = in + (size_t)b*K_FEAT + p;
    float v[32];
    #pragma unroll
    for (int c = 0; c < 32; ++c) v[c] = ip[c*K_P];
    float m = v[0];
    #pragma unroll
    for (int c = 1; c < 32; ++c) m = fmaxf(m, v[c]);
    float s = 0.f;
    #pragma unroll
    for (int c = 0; c < 32; ++c) { v[c] = __expf(beta*(v[c]-m)); s += v[c]; }
    float inv = 1.0f / s;
    short* op = out + (size_t)b*K_FEAT + p;
    #pragma unroll
    for (int c = 0; c < 32; ++c) op[c*K_P] = f2bf(v[c]*inv);
}

// ---------------------------------------------------------------- channel softmax fp32 (for convT input)
__global__ __launch_bounds__(256) void softmax_ch(const float* __restrict__ in,
                                                  float* __restrict__ out, float beta) {
    int tid = blockIdx.x*256 + threadIdx.x;
    if (tid >= K_B*K_P) return;
    int b = tid / K_P, p = tid - b*K_P;
    const float* ip = in + (size_t)b*K_FEAT + p;
    float v[32];
    #pragma unroll
    for (int c = 0; c < 32; ++c) v[c] = ip[c*K_P];
    float m = v[0];
    #pragma unroll
    for (int c = 1; c < 32; ++c) m = fmaxf(m, v[c]);
    float s = 0.f;
    #pragma unroll
    for (int c = 0; c < 32; ++c) { v[c] = __expf(beta*(v[c]-m)); s += v[c]; }
    float inv = 1.0f / s;
    float* op = out + (size_t)b*K_FEAT + p;
    #pragma unroll
    for (int c = 0; c < 32; ++c) op[c*K_P] = v[c]*inv;
}

// ---------------------------------------------------------------- GEMM1 (MFMA): z[b][zi] = sum_f W[zi][f]*fy[b][f]
// grid (4 zi-blocks, 55 k-splits), 256 thr = 4 waves; wave = 16 zi x 32 b over 1760 k.
// D = A*B: A[m=zi][k]=Wb row (contig), B[k][n=b]=fyb row (contig). fp32 atomics into z.
__global__ __launch_bounds__(256) void gemm1_mfma(const short* __restrict__ Wb,
                                                  const short* __restrict__ fyb,
                                                  float* __restrict__ z) {
    int t = threadIdx.x;
    int wid = t >> 6, l = t & 63;
    int lr = l & 15, lg = l >> 4;
    int zi0 = blockIdx.x*64 + wid*16;
    int k0  = blockIdx.y*1760;            // 55 k-steps of 32
    const short* Ap  = Wb  + (size_t)(zi0 + lr)*K_FEAT + k0 + lg*8;
    const short* Bp0 = fyb + (size_t)(lr)*K_FEAT      + k0 + lg*8;
    const short* Bp1 = fyb + (size_t)(16 + lr)*K_FEAT + k0 + lg*8;
    f32x4 acc0 = {0.f,0.f,0.f,0.f}, acc1 = {0.f,0.f,0.f,0.f};
    #pragma unroll 5
    for (int k = 0; k < 55; ++k) {
        short8 a  = *(const short8*)(Ap  + k*32);
        short8 b0 = *(const short8*)(Bp0 + k*32);
        short8 b1 = *(const short8*)(Bp1 + k*32);
        acc0 = __builtin_amdgcn_mfma_f32_16x16x32_bf16(a, b0, acc0, 0, 0, 0);
        acc1 = __builtin_amdgcn_mfma_f32_16x16x32_bf16(a, b1, acc1, 0, 0, 0);
    }
    // D lane l reg r: col(b)=lr, row(zi)=lg*4+r
    #pragma unroll
    for (int r = 0; r < 4; ++r) {
        atomicAdd(&z[(size_t)(lr)*K_Z      + zi0 + lg*4 + r], acc0[r]);
        atomicAdd(&z[(size_t)(16+lr)*K_Z   + zi0 + lg*4 + r], acc1[r]);
    }
}

// ---------------------------------------------------------------- softmax over z slots -> bf16 fz [b][z]
__global__ __launch_bounds__(256) void softmax_fz(const float* __restrict__ z,
                                                  short* __restrict__ fzb) {
    __shared__ float sr[256];
    int b = blockIdx.x, t = threadIdx.x;
    float v = 7.0f * z[b*K_Z + t];
    sr[t] = v; __syncthreads();
    for (int off = 128; off > 0; off >>= 1) {
        if (t < off) sr[t] = fmaxf(sr[t], sr[t+off]);
        __syncthreads();
    }
    float m = sr[0];
    __syncthreads();
    float e = __expf(v - m);
    sr[t] = e; __syncthreads();
    for (int off = 128; off > 0; off >>= 1) {
        if (t < off) sr[t] += sr[t+off];
        __syncthreads();
    }
    float s = sr[0];
    fzb[b*K_Z + t] = f2bf(e / s);
}

// ---------------------------------------------------------------- GEMM2 (MFMA) + y update:
// top[b][f] = sum_z W[z][f]*fz[b][z];  y = 0.5*(y + conv_x + top)
// grid 757 blocks x 4 waves; wave = 32 b x 32 f over K=256.
// A[m=b][k=z]=fzb (contig). B[k=z][n=f]=Wb column-ish: 8 strided u16/lane.
__global__ __launch_bounds__(256) void gemm2_mfma(const short* __restrict__ Wb,
                                                  const short* __restrict__ fzb,
                                                  const float* __restrict__ cxb,
                                                  float* __restrict__ y) {
    int t = threadIdx.x;
    int wid = t >> 6, l = t & 63;
    int lr = l & 15, lg = l >> 4;
    int f0 = blockIdx.x*128 + wid*32;
    if (f0 >= K_FEAT) return;
    // hoist A fragments: 2 m-tiles x 8 k-steps (same for all blocks; L2-hot)
    const short* A0 = fzb + (size_t)(lr)*K_Z      + lg*8;
    const short* A1 = fzb + (size_t)(16 + lr)*K_Z + lg*8;
    short8 af0[8], af1[8];
    #pragma unroll
    for (int k = 0; k < 8; ++k) {
        af0[k] = *(const short8*)(A0 + k*32);
        af1[k] = *(const short8*)(A1 + k*32);
    }
    f32x4 acc[2][2] = {{{0.f,0.f,0.f,0.f},{0.f,0.f,0.f,0.f}},
                       {{0.f,0.f,0.f,0.f},{0.f,0.f,0.f,0.f}}};
    #pragma unroll
    for (int nt = 0; nt < 2; ++nt) {
        int f1 = f0 + nt*16;
        #pragma unroll
        for (int k = 0; k < 8; ++k) {
            const short* bp = Wb + (size_t)(k*32 + lg*8)*K_FEAT + f1 + lr;
            short8 b;
            #pragma unroll
            for (int j = 0; j < 8; ++j) b[j] = bp[(size_t)j*K_FEAT];
            acc[0][nt] = __builtin_amdgcn_mfma_f32_16x16x32_bf16(af0[k], b, acc[0][nt], 0, 0, 0);
            acc[1][nt] = __builtin_amdgcn_mfma_f32_16x16x32_bf16(af1[k], b, acc[1][nt], 0, 0, 0);
        }
    }
    // D lane l reg r: col(f)=f1+lr, row(b)=mt*16+lg*4+r
    #pragma unroll
    for (int mt = 0; mt < 2; ++mt) {
        #pragma unroll
        for (int nt = 0; nt < 2; ++nt) {
            #pragma unroll
            for (int r = 0; r < 4; ++r) {
                int bb = mt*16 + lg*4 + r;
                size_t idx = (size_t)bb*K_FEAT + f0 + nt*16 + lr;
                y[idx] = 0.5f*(y[idx] + cxb[idx] + acc[mt][nt][r]);
            }
        }
    }
}

// ---------------------------------------------------------------- forward conv (fp32, unchanged)
__global__ __launch_bounds__(256) void conv_fwd(const float* __restrict__ x,
                                                const float* __restrict__ KwT1,
                                                float* __restrict__ out) {
    __shared__ __align__(16) float kws[9600];
    __shared__ float xs[1020];                      // [3][17][20]
    int t = threadIdx.x;
    int b = blockIdx.y;
    int tile = blockIdx.x;
    int ty0 = (tile/7)*8, tx0 = (tile%7)*8;
    for (int i = t; i < 9600; i += 256) kws[i] = KwT1[i];
    for (int i = t; i < 1020; i += 256) {
        int cxi = i/340, rem = i - cxi*340, rr = rem/20, cc = rem - rr*20;
        float v = 0.f;
        int row = ty0+rr, col = tx0+cc;
        if (cc < 17 && row < 64 && col < 64) v = x[b*K_XN + cxi*4096 + row*64 + col];
        xs[i] = v;
    }
    __syncthreads();
    int pix = t & 63, px = pix & 7, py = pix >> 3;
    int cy0 = (t >> 6) * 8;
    float acc[8];
    #pragma unroll
    for (int i = 0; i < 8; ++i) acc[i] = 0.f;
    for (int cxi = 0; cxi < 3; ++cxi)
      for (int ky = 0; ky < 10; ++ky) {
        const float* xr = &xs[cxi*340 + (py+ky)*20 + px];
        const float* kr = &kws[(cxi*100 + ky*10)*32 + cy0];
        #pragma unroll
        for (int kx = 0; kx < 10; ++kx) {
            float xv = xr[kx];
            float4 a  = *(const float4*)(kr + kx*32);
            float4 b4 = *(const float4*)(kr + kx*32 + 4);
            acc[0] += xv*a.x;  acc[1] += xv*a.y;  acc[2] += xv*a.z;  acc[3] += xv*a.w;
            acc[4] += xv*b4.x; acc[5] += xv*b4.y; acc[6] += xv*b4.z; acc[7] += xv*b4.w;
        }
      }
    int oy = ty0+py, ox = tx0+px;
    if (oy < 55 && ox < 55) {
        int base = b*K_FEAT + cy0*K_P + oy*55 + ox;
        #pragma unroll
        for (int i = 0; i < 8; ++i) out[base + i*K_P] = acc[i];
    }
}

// ---------------------------------------------------------------- x *= 0.9
__global__ __launch_bounds__(256) void x_scale(float* __restrict__ x) {
    int i = blockIdx.x*256 + threadIdx.x;
    x[i] *= 0.9f;
}

// ---------------------------------------------------------------- adjoint conv (fp32, unchanged)
__global__ __launch_bounds__(256) void convT(const float* __restrict__ sy,
                                             const float* __restrict__ KwT2,
                                             float* __restrict__ x) {
    __shared__ __align__(16) float kws[3200];       // [8cy][10][10][4]
    __shared__ float sys[14432];                    // [8cy][41][44]
    int t = threadIdx.x;
    int tile = blockIdx.x;
    int ti0 = (tile >> 1)*32, tj0 = (tile & 1)*32;
    int cy0 = blockIdx.y * 8;
    int b = blockIdx.z;
    for (int i = t; i < 3200; i += 256) kws[i] = KwT2[cy0*400 + i];
    for (int i = t; i < 14432; i += 256) {
        int cyi = i / 1804, rem = i - cyi*1804, rr = rem/44, cc = rem - rr*44;
        if (cc < 41) {
            int row = ti0 + rr - 9, col = tj0 + cc - 9;
            float v = (row >= 0 && row < 55 && col >= 0 && col < 55)
                        ? sy[(size_t)b*K_FEAT + (cy0+cyi)*K_P + row*55 + col] : 0.f;
            sys[i] = v;
        }
    }
    __syncthreads();
    int px = t & 31, py0 = (t >> 5)*4;
    float acc[12];
    #pragma unroll
    for (int i = 0; i < 12; ++i) acc[i] = 0.f;
    for (int cyi = 0; cyi < 8; ++cyi) {
        for (int kx = 0; kx < 10; ++kx) {
            float4 kw[10];
            #pragma unroll
            for (int ky = 0; ky < 10; ++ky) kw[ky] = *(const float4*)&kws[((cyi*10+ky)*10 + kx)*4];
            const float* sp = &sys[cyi*1804 + px + kx];
            #pragma unroll
            for (int rr = 0; rr < 13; ++rr) {
                float sv = sp[(py0 + rr)*44];
                #pragma unroll
                for (int i = 0; i < 4; ++i) {
                    int ky = rr - i;
                    if (ky >= 0 && ky < 10) {
                        acc[i*3+0] += sv*kw[ky].x;
                        acc[i*3+1] += sv*kw[ky].y;
                        acc[i*3+2] += sv*kw[ky].z;
                    }
                }
            }
        }
    }
    int gb = b*K_XN;
    #pragma unroll
    for (int i = 0; i < 4; ++i) {
        int row = ti0 + py0 + i, col = tj0 + px;
        #pragma unroll
        for (int c = 0; c < 3; ++c)
            atomicAdd(&x[gb + c*4096 + row*64 + col], 0.1f*acc[i*3+c]);
    }
}

// ----------------------------------------------------------------
extern "C" void kernel_launch(void* const* d_in, const int* in_sizes, int n_in,
                              void* d_out, int out_size, void* d_ws, size_t ws_size,
                              hipStream_t stream) {
    const float* xin = (const float*)d_in[0];   // [32,3,64,64]
    const float* Kw  = (const float*)d_in[1];   // [32,3,10,10]
    const float* W   = (const float*)d_in[2];   // [256,96800]
    float* x = (float*)d_out;                   // x state lives in d_out

    float* ws   = (float*)d_ws;
    float* y    = ws;                           // 3,097,600 f
    float* sy   = y    + 3097600;               // 3,097,600 f
    float* cxb  = sy   + 3097600;               // 3,097,600 f
    float* z    = cxb  + 3097600;               // 8192 f
    float* KwT1 = z    + 8192;                  // 9600 f
    float* KwT2 = KwT1 + 9600;                  // 12800 f
    short* fyb  = (short*)(KwT2 + 12800);       // 3,097,600 shorts
    short* fzb  = fyb + 3097600;                // 8192 shorts
    short* Wb   = fzb + 8192;                   // 24,780,800 shorts

    hipMemcpyAsync(x, xin, (size_t)K_B*K_XN*sizeof(float), hipMemcpyDeviceToDevice, stream);
    hipMemsetAsync(y, 0, (size_t)3097600*sizeof(float), stream);
    prep_kw<<<88, 256, 0, stream>>>(Kw, KwT1, KwT2);
    w_to_bf16<<<12100, 256, 0, stream>>>(W, Wb);

    for (int s = 0; s < 30; ++s) {
        conv_fwd<<<dim3(49,32), 256, 0, stream>>>(x, KwT1, cxb);
        x_scale<<<1536, 256, 0, stream>>>(x);
        softmax_ch_bf<<<379, 256, 0, stream>>>(y, fyb, 3.0f);
        hipMemsetAsync(z, 0, 8192*sizeof(float), stream);
        gemm1_mfma<<<dim3(4,55), 256, 0, stream>>>(Wb, fyb, z);
        softmax_fz<<<32, 256, 0, stream>>>(z, fzb);
        gemm2_mfma<<<757, 256, 0, stream>>>(Wb, fzb, cxb, y);
        softmax_ch<<<379, 256, 0, stream>>>(y, sy, 1.0f);
        convT<<<dim3(4,4,32), 256, 0, stream>>>(sy, KwT2, x);
    }
}

// Round 3
// 5113.729 us; speedup vs baseline: 1.7465x; 1.1451x over previous
//
#include <hip/hip_runtime.h>

#define K_B    32
#define K_CXC  3
#define K_XS   64
#define K_CY   32
#define K_KS   10
#define K_M    55
#define K_Z    256
#define K_P    (K_M*K_M)          // 3025
#define K_FEAT (K_CY*K_P)         // 96800
#define K_XN   (K_CXC*K_XS*K_XS)  // 12288 per batch
#define K_NSPLIT 55               // gemm1 k-splits

typedef __attribute__((ext_vector_type(8))) short short8;
typedef __attribute__((ext_vector_type(4))) float f32x4;

__device__ __forceinline__ short f2bf(float f) {
    unsigned u = __builtin_bit_cast(unsigned, f);
    unsigned r = (u + 0x7FFFu + ((u >> 16) & 1u)) >> 16;
    return (short)r;
}

// ---------------------------------------------------------------- once: W fp32 -> bf16 row-major (gemm1 A)
__global__ __launch_bounds__(256) void w_to_bf16(const float* __restrict__ W,
                                                 short* __restrict__ Wb) {
    size_t i = ((size_t)blockIdx.x*256 + threadIdx.x) * 8;
    float4 a = *(const float4*)(W + i);
    float4 b = *(const float4*)(W + i + 4);
    short8 o;
    o[0]=f2bf(a.x); o[1]=f2bf(a.y); o[2]=f2bf(a.z); o[3]=f2bf(a.w);
    o[4]=f2bf(b.x); o[5]=f2bf(b.y); o[6]=f2bf(b.z); o[7]=f2bf(b.w);
    *(short8*)(Wb + i) = o;
}

// ---------------------------------------------------------------- once: W -> Wg2[z/8][f][8] bf16 (gemm2 B, coalesced)
__global__ __launch_bounds__(256) void w_to_g2(const float* __restrict__ W,
                                               short* __restrict__ Wg2) {
    int f = blockIdx.x*256 + threadIdx.x;
    if (f >= K_FEAT) return;
    int zb = blockIdx.y;
    short8 o;
    #pragma unroll
    for (int j = 0; j < 8; ++j) o[j] = f2bf(W[(size_t)(zb*8 + j)*K_FEAT + f]);
    *(short8*)(Wg2 + ((size_t)zb*K_FEAT + f)*8) = o;
}

// ---------------------------------------------------------------- once: kernel transposes
__global__ __launch_bounds__(256) void prep_kw(const float* __restrict__ Kw,
                                               float* __restrict__ KwT1,
                                               float* __restrict__ KwT2) {
    int idx = blockIdx.x*256 + threadIdx.x;
    if (idx < 9600) {
        int cy = idx & 31, s = idx >> 5;
        KwT1[idx] = Kw[cy*300 + s];
    } else if (idx < 9600 + 12800) {
        int o = idx - 9600;
        int c = o & 3, s = o >> 2;
        int kx = s % 10, ky = (s/10) % 10, cy = s/100;
        KwT2[o] = (c < 3) ? Kw[cy*300 + c*100 + (9-ky)*10 + (9-kx)] : 0.0f;
    }
}

// ---------------------------------------------------------------- once: fyb = softmax(0) = 1/32 (bf16 0x3D00)
__global__ __launch_bounds__(256) void fyb_fill(short* __restrict__ fyb) {
    size_t i = ((size_t)blockIdx.x*256 + threadIdx.x) * 8;
    short8 o = {0x3D00,0x3D00,0x3D00,0x3D00,0x3D00,0x3D00,0x3D00,0x3D00};
    *(short8*)(fyb + i) = o;
}

// ---------------------------------------------------------------- fused A: conv_fwd (blocks 0..1567) + gemm1 (1568..1787)
// conv: out cxb[b][cy][55][55]. gemm1: zpart[ks][b][zi] = partial of W.fy over 1760 k.
__global__ __launch_bounds__(256) void fused_A(const float* __restrict__ x,
                                               const float* __restrict__ KwT1,
                                               float* __restrict__ cxb,
                                               const short* __restrict__ Wb,
                                               const short* __restrict__ fyb,
                                               float* __restrict__ zpart) {
    __shared__ __align__(16) float kws[9600];
    __shared__ float xs[1020];                      // [3][17][20]
    int bid = blockIdx.x;
    int t = threadIdx.x;
    if (bid < 1568) {
        // ---------------- conv_fwd ----------------
        int b = bid / 49;
        int tile = bid - b*49;
        int ty0 = (tile/7)*8, tx0 = (tile%7)*8;
        for (int i = t; i < 9600; i += 256) kws[i] = KwT1[i];
        for (int i = t; i < 1020; i += 256) {
            int cxi = i/340, rem = i - cxi*340, rr = rem/20, cc = rem - rr*20;
            float v = 0.f;
            int row = ty0+rr, col = tx0+cc;
            if (cc < 17 && row < 64 && col < 64) v = x[b*K_XN + cxi*4096 + row*64 + col];
            xs[i] = v;
        }
        __syncthreads();
        int pix = t & 63, px = pix & 7, py = pix >> 3;
        int cy0 = (t >> 6) * 8;
        float acc[8];
        #pragma unroll
        for (int i = 0; i < 8; ++i) acc[i] = 0.f;
        for (int cxi = 0; cxi < 3; ++cxi)
          for (int ky = 0; ky < 10; ++ky) {
            const float* xr = &xs[cxi*340 + (py+ky)*20 + px];
            const float* kr = &kws[(cxi*100 + ky*10)*32 + cy0];
            #pragma unroll
            for (int kx = 0; kx < 10; ++kx) {
                float xv = xr[kx];
                float4 a  = *(const float4*)(kr + kx*32);
                float4 b4 = *(const float4*)(kr + kx*32 + 4);
                acc[0] += xv*a.x;  acc[1] += xv*a.y;  acc[2] += xv*a.z;  acc[3] += xv*a.w;
                acc[4] += xv*b4.x; acc[5] += xv*b4.y; acc[6] += xv*b4.z; acc[7] += xv*b4.w;
            }
          }
        int oy = ty0+py, ox = tx0+px;
        if (oy < 55 && ox < 55) {
            int base = b*K_FEAT + cy0*K_P + oy*55 + ox;
            #pragma unroll
            for (int i = 0; i < 8; ++i) cxb[base + i*K_P] = acc[i];
        }
    } else {
        // ---------------- gemm1 (MFMA, k-split partials) ----------------
        int g = bid - 1568;                 // 220 = 4 x 55
        int bx = g & 3, by = g >> 2;
        int wid = t >> 6, l = t & 63;
        int lr = l & 15, lg = l >> 4;
        int zi0 = bx*64 + wid*16;
        int k0  = by*1760;
        const short* Ap  = Wb  + (size_t)(zi0 + lr)*K_FEAT + k0 + lg*8;
        const short* Bp0 = fyb + (size_t)(lr)*K_FEAT      + k0 + lg*8;
        const short* Bp1 = fyb + (size_t)(16 + lr)*K_FEAT + k0 + lg*8;
        f32x4 acc0 = {0.f,0.f,0.f,0.f}, acc1 = {0.f,0.f,0.f,0.f};
        #pragma unroll 5
        for (int k = 0; k < 55; ++k) {
            short8 a  = *(const short8*)(Ap  + k*32);
            short8 b0 = *(const short8*)(Bp0 + k*32);
            short8 b1 = *(const short8*)(Bp1 + k*32);
            acc0 = __builtin_amdgcn_mfma_f32_16x16x32_bf16(a, b0, acc0, 0, 0, 0);
            acc1 = __builtin_amdgcn_mfma_f32_16x16x32_bf16(a, b1, acc1, 0, 0, 0);
        }
        float* zp = zpart + (size_t)by*8192;
        #pragma unroll
        for (int r = 0; r < 4; ++r) {
            zp[(lr)*K_Z    + zi0 + lg*4 + r] = acc0[r];
            zp[(16+lr)*K_Z + zi0 + lg*4 + r] = acc1[r];
        }
    }
}

// ---------------------------------------------------------------- softmax_fz (blocks 0..31) + x_scale (32..1567)
__global__ __launch_bounds__(256) void fz_xscale(const float* __restrict__ zpart,
                                                 short* __restrict__ fzb,
                                                 float* __restrict__ x) {
    __shared__ float sr[256];
    int bid = blockIdx.x, t = threadIdx.x;
    if (bid < 32) {
        int b = bid;
        float zv = 0.f;
        #pragma unroll 5
        for (int p = 0; p < K_NSPLIT; ++p) zv += zpart[(size_t)p*8192 + b*K_Z + t];
        float v = 7.0f * zv;
        sr[t] = v; __syncthreads();
        for (int off = 128; off > 0; off >>= 1) {
            if (t < off) sr[t] = fmaxf(sr[t], sr[t+off]);
            __syncthreads();
        }
        float m = sr[0];
        __syncthreads();
        float e = __expf(v - m);
        sr[t] = e; __syncthreads();
        for (int off = 128; off > 0; off >>= 1) {
            if (t < off) sr[t] += sr[t+off];
            __syncthreads();
        }
        float s = sr[0];
        fzb[b*K_Z + t] = f2bf(e / s);
    } else {
        int i = (bid - 32)*256 + t;
        x[i] *= 0.9f;
    }
}

// ---------------------------------------------------------------- GEMM2 (MFMA, coalesced B) + y update
__global__ __launch_bounds__(256) void gemm2_mfma(const short* __restrict__ Wg2,
                                                  const short* __restrict__ fzb,
                                                  const float* __restrict__ cxb,
                                                  float* __restrict__ y) {
    int t = threadIdx.x;
    int wid = t >> 6, l = t & 63;
    int lr = l & 15, lg = l >> 4;
    int f0 = blockIdx.x*128 + wid*32;
    if (f0 >= K_FEAT) return;
    const short* A0 = fzb + (size_t)(lr)*K_Z      + lg*8;
    const short* A1 = fzb + (size_t)(16 + lr)*K_Z + lg*8;
    short8 af0[8], af1[8];
    #pragma unroll
    for (int k = 0; k < 8; ++k) {
        af0[k] = *(const short8*)(A0 + k*32);
        af1[k] = *(const short8*)(A1 + k*32);
    }
    f32x4 acc[2][2] = {{{0.f,0.f,0.f,0.f},{0.f,0.f,0.f,0.f}},
                       {{0.f,0.f,0.f,0.f},{0.f,0.f,0.f,0.f}}};
    #pragma unroll
    for (int nt = 0; nt < 2; ++nt) {
        int f1 = f0 + nt*16;
        #pragma unroll
        for (int k = 0; k < 8; ++k) {
            // zb = k*4 + lg ; contiguous short8 per lane
            const short* bp = Wg2 + ((size_t)(k*4 + lg)*K_FEAT + f1 + lr)*8;
            short8 b = *(const short8*)bp;
            acc[0][nt] = __builtin_amdgcn_mfma_f32_16x16x32_bf16(af0[k], b, acc[0][nt], 0, 0, 0);
            acc[1][nt] = __builtin_amdgcn_mfma_f32_16x16x32_bf16(af1[k], b, acc[1][nt], 0, 0, 0);
        }
    }
    #pragma unroll
    for (int mt = 0; mt < 2; ++mt) {
        #pragma unroll
        for (int nt = 0; nt < 2; ++nt) {
            #pragma unroll
            for (int r = 0; r < 4; ++r) {
                int bb = mt*16 + lg*4 + r;
                size_t idx = (size_t)bb*K_FEAT + f0 + nt*16 + lr;
                y[idx] = 0.5f*(y[idx] + cxb[idx] + acc[mt][nt][r]);
            }
        }
    }
}

// ---------------------------------------------------------------- dual channel softmax: y -> sy (beta=1, fp32) + fyb (beta=3, bf16)
__global__ __launch_bounds__(256) void softmax_dual(const float* __restrict__ y,
                                                    float* __restrict__ sy,
                                                    short* __restrict__ fyb) {
    int tid = blockIdx.x*256 + threadIdx.x;
    if (tid >= K_B*K_P) return;
    int b = tid / K_P, p = tid - b*K_P;
    const float* ip = y + (size_t)b*K_FEAT + p;
    float v[32];
    #pragma unroll
    for (int c = 0; c < 32; ++c) v[c] = ip[c*K_P];
    float m = v[0];
    #pragma unroll
    for (int c = 1; c < 32; ++c) m = fmaxf(m, v[c]);
    float e1[32];
    float s1 = 0.f, s3 = 0.f;
    #pragma unroll
    for (int c = 0; c < 32; ++c) {
        float d = v[c] - m;
        float a1 = __expf(d);
        float a3 = __expf(3.0f*d);
        e1[c] = a1; v[c] = a3;
        s1 += a1; s3 += a3;
    }
    float i1 = 1.0f/s1, i3 = 1.0f/s3;
    float* op = sy + (size_t)b*K_FEAT + p;
    short* fp = fyb + (size_t)b*K_FEAT + p;
    #pragma unroll
    for (int c = 0; c < 32; ++c) {
        op[c*K_P] = e1[c]*i1;
        fp[c*K_P] = f2bf(v[c]*i3);
    }
}

// ---------------------------------------------------------------- adjoint conv (fp32), atomic += 0.1*x_inst
__global__ __launch_bounds__(256) void convT(const float* __restrict__ sy,
                                             const float* __restrict__ KwT2,
                                             float* __restrict__ x) {
    __shared__ __align__(16) float kws[3200];       // [8cy][10][10][4]
    __shared__ float sys[14432];                    // [8cy][41][44]
    int t = threadIdx.x;
    int tile = blockIdx.x;
    int ti0 = (tile >> 1)*32, tj0 = (tile & 1)*32;
    int cy0 = blockIdx.y * 8;
    int b = blockIdx.z;
    for (int i = t; i < 3200; i += 256) kws[i] = KwT2[cy0*400 + i];
    for (int i = t; i < 14432; i += 256) {
        int cyi = i / 1804, rem = i - cyi*1804, rr = rem/44, cc = rem - rr*44;
        if (cc < 41) {
            int row = ti0 + rr - 9, col = tj0 + cc - 9;
            float v = (row >= 0 && row < 55 && col >= 0 && col < 55)
                        ? sy[(size_t)b*K_FEAT + (cy0+cyi)*K_P + row*55 + col] : 0.f;
            sys[i] = v;
        }
    }
    __syncthreads();
    int px = t & 31, py0 = (t >> 5)*4;
    float acc[12];
    #pragma unroll
    for (int i = 0; i < 12; ++i) acc[i] = 0.f;
    for (int cyi = 0; cyi < 8; ++cyi) {
        for (int kx = 0; kx < 10; ++kx) {
            float4 kw[10];
            #pragma unroll
            for (int ky = 0; ky < 10; ++ky) kw[ky] = *(const float4*)&kws[((cyi*10+ky)*10 + kx)*4];
            const float* sp = &sys[cyi*1804 + px + kx];
            #pragma unroll
            for (int rr = 0; rr < 13; ++rr) {
                float sv = sp[(py0 + rr)*44];
                #pragma unroll
                for (int i = 0; i < 4; ++i) {
                    int ky = rr - i;
                    if (ky >= 0 && ky < 10) {
                        acc[i*3+0] += sv*kw[ky].x;
                        acc[i*3+1] += sv*kw[ky].y;
                        acc[i*3+2] += sv*kw[ky].z;
                    }
                }
            }
        }
    }
    int gb = b*K_XN;
    #pragma unroll
    for (int i = 0; i < 4; ++i) {
        int row = ti0 + py0 + i, col = tj0 + px;
        #pragma unroll
        for (int c = 0; c < 3; ++c)
            atomicAdd(&x[gb + c*4096 + row*64 + col], 0.1f*acc[i*3+c]);
    }
}

// ----------------------------------------------------------------
extern "C" void kernel_launch(void* const* d_in, const int* in_sizes, int n_in,
                              void* d_out, int out_size, void* d_ws, size_t ws_size,
                              hipStream_t stream) {
    const float* xin = (const float*)d_in[0];   // [32,3,64,64]
    const float* Kw  = (const float*)d_in[1];   // [32,3,10,10]
    const float* W   = (const float*)d_in[2];   // [256,96800]
    float* x = (float*)d_out;                   // x state lives in d_out

    float* ws    = (float*)d_ws;
    float* y     = ws;                          // 3,097,600 f
    float* sy    = y     + 3097600;             // 3,097,600 f
    float* cxb   = sy    + 3097600;             // 3,097,600 f
    float* zpart = cxb   + 3097600;             // 55*8192 = 450,560 f
    float* KwT1  = zpart + 450560;              // 9600 f
    float* KwT2  = KwT1  + 9600;                // 12800 f
    short* fyb   = (short*)(KwT2 + 12800);      // 3,097,600 s
    short* fzb   = fyb + 3097600;               // 8192 s
    short* Wb    = fzb + 8192;                  // 24,780,800 s
    short* Wg2   = Wb  + 24780800;              // 24,780,800 s

    hipMemcpyAsync(x, xin, (size_t)K_B*K_XN*sizeof(float), hipMemcpyDeviceToDevice, stream);
    hipMemsetAsync(y, 0, (size_t)3097600*sizeof(float), stream);
    prep_kw<<<88, 256, 0, stream>>>(Kw, KwT1, KwT2);
    w_to_bf16<<<12100, 256, 0, stream>>>(W, Wb);
    w_to_g2<<<dim3(379,32), 256, 0, stream>>>(W, Wg2);
    fyb_fill<<<1513, 256, 0, stream>>>(fyb);

    for (int s = 0; s < 30; ++s) {
        fused_A<<<1788, 256, 0, stream>>>(x, KwT1, cxb, Wb, fyb, zpart);
        fz_xscale<<<1568, 256, 0, stream>>>(zpart, fzb, x);
        gemm2_mfma<<<757, 256, 0, stream>>>(Wg2, fzb, cxb, y);
        softmax_dual<<<379, 256, 0, stream>>>(y, sy, fyb);
        convT<<<dim3(4,4,32), 256, 0, stream>>>(sy, KwT2, x);
    }
}

// Round 4
// 3205.956 us; speedup vs baseline: 2.7858x; 1.5951x over previous
//
#include <hip/hip_runtime.h>

#define K_B    32
#define K_CXC  3
#define K_XS   64
#define K_CY   32
#define K_M    55
#define K_Z    256
#define K_P    (K_M*K_M)          // 3025
#define K_FEAT (K_CY*K_P)         // 96800
#define K_XN   (K_CXC*K_XS*K_XS)  // 12288 per batch
#define K_NSPLIT 55               // gemm1 k-splits

typedef __attribute__((ext_vector_type(8))) short short8;
typedef __attribute__((ext_vector_type(4))) float f32x4;

__device__ __forceinline__ short f2bf(float f) {
    unsigned u = __builtin_bit_cast(unsigned, f);
    unsigned r = (u + 0x7FFFu + ((u >> 16) & 1u)) >> 16;
    return (short)r;
}

// ---------------------------------------------------------------- once: W fp32 -> bf16 row-major (gemm1 A)
__global__ __launch_bounds__(256) void w_to_bf16(const float* __restrict__ W,
                                                 short* __restrict__ Wb) {
    size_t i = ((size_t)blockIdx.x*256 + threadIdx.x) * 8;
    float4 a = *(const float4*)(W + i);
    float4 b = *(const float4*)(W + i + 4);
    short8 o;
    o[0]=f2bf(a.x); o[1]=f2bf(a.y); o[2]=f2bf(a.z); o[3]=f2bf(a.w);
    o[4]=f2bf(b.x); o[5]=f2bf(b.y); o[6]=f2bf(b.z); o[7]=f2bf(b.w);
    *(short8*)(Wb + i) = o;
}

// ---------------------------------------------------------------- once: W -> Wg2[z/8][f][8] bf16 (gemm2 B)
__global__ __launch_bounds__(256) void w_to_g2(const float* __restrict__ W,
                                               short* __restrict__ Wg2) {
    int f = blockIdx.x*256 + threadIdx.x;
    if (f >= K_FEAT) return;
    int zb = blockIdx.y;
    short8 o;
    #pragma unroll
    for (int j = 0; j < 8; ++j) o[j] = f2bf(W[(size_t)(zb*8 + j)*K_FEAT + f]);
    *(short8*)(Wg2 + ((size_t)zb*K_FEAT + f)*8) = o;
}

// ---------------------------------------------------------------- once: per-lane MFMA kernel-fragment tables
// KfragT[u][v][lane][8]: A[m=cx][k=cy] for convT tap (u,v), Wf = Kw flipped
// Kfrag2[ks][nt][lane][8]: A[m=cy][k=(cx,u,v16)] for conv_fwd k-step ks, cy-half nt
__global__ __launch_bounds__(256) void prep_frags(const float* __restrict__ Kw,
                                                  short* __restrict__ KfragT,
                                                  short* __restrict__ Kfrag2) {
    int e = blockIdx.x*256 + threadIdx.x;
    if (e < 6400) {
        int uv = e >> 6, l = e & 63;
        int u = uv / 10, v = uv - u*10;
        int lr = l & 15, lg = l >> 4;
        short8 o;
        #pragma unroll
        for (int j = 0; j < 8; ++j) {
            int cy = lg*8 + j;
            o[j] = (lr < 3) ? f2bf(Kw[cy*300 + lr*100 + (9-u)*10 + (9-v)]) : (short)0;
        }
        *(short8*)(KfragT + (size_t)e*8) = o;
    } else if (e < 6400 + 1920) {
        int e2 = e - 6400;
        int kn = e2 >> 6, l = e2 & 63;
        int ks = kn >> 1, nt = kn & 1;
        int lr = l & 15, lg = l >> 4;
        short8 o;
        #pragma unroll
        for (int j = 0; j < 8; ++j) {
            int k = ks*32 + lg*8 + j;
            int cx = k / 160, rem = k - cx*160;
            int u = rem >> 4, v = rem & 15;
            o[j] = (v < 10) ? f2bf(Kw[(lr + nt*16)*300 + cx*100 + u*10 + v]) : (short)0;
        }
        *(short8*)(Kfrag2 + (size_t)e2*8) = o;
    }
}

// ---------------------------------------------------------------- once: fyb = softmax(0) = 1/32
__global__ __launch_bounds__(256) void fyb_fill(short* __restrict__ fyb) {
    size_t i = ((size_t)blockIdx.x*256 + threadIdx.x) * 8;
    if (i >= (size_t)K_B*K_FEAT) return;
    short8 o = {0x3D00,0x3D00,0x3D00,0x3D00,0x3D00,0x3D00,0x3D00,0x3D00};
    *(short8*)(fyb + i) = o;
}

// ---------------------------------------------------------------- fused A: conv_fwd MFMA (0..511) + gemm1 (512..731)
__global__ __launch_bounds__(256) void fused_A(const float* __restrict__ x,
                                               float* __restrict__ cxb,
                                               const short* __restrict__ Wb,
                                               const short* __restrict__ fyb,
                                               float* __restrict__ zpart,
                                               const short* __restrict__ Kfrag2) {
    __shared__ __align__(16) short lds[29760];   // 14400 x-shift-copies + 15360 Kfrag2
    int bid = blockIdx.x;
    int t = threadIdx.x;
    if (bid < 512) {
        // ---------------- conv_fwd: cxb[b,cy,i,j] = sum_{cx,u,v} x[b,cx,i+u,j+v]Kw[cy,cx,u,v]
        short* xcopy = lds;           // addr16 = s*225 + cx*75 + row*3 + i16  (1800 x 16B)
        short* kf = lds + 14400;      // [ks][nt][lane][8] (1920 x 16B)
        int b = bid >> 4, tile = bid & 15;
        int i0 = (tile >> 2) * 16, j0 = (tile & 3) * 16;
        const float* xb = x + (size_t)b*K_XN;
        for (int e = t; e < 1800; e += 256) {
            int s = e / 225, rem = e - s*225;
            int cx = rem / 75, r2 = rem - cx*75;
            int row = r2 / 3, i16 = r2 - row*3;
            int gr = i0 + row;
            int gc0 = j0 + i16*8 + s;
            const float* xp = xb + cx*4096 + gr*64;
            short8 o;
            #pragma unroll
            for (int j = 0; j < 8; ++j) {
                int gc = gc0 + j;
                float v = (gr < 64 && gc < 64) ? xp[gc] : 0.f;
                o[j] = f2bf(v);
            }
            *(short8*)(xcopy + (size_t)e*8) = o;
        }
        for (int e = t; e < 1920; e += 256)
            *(short8*)(kf + (size_t)e*8) = *(const short8*)(Kfrag2 + (size_t)e*8);
        __syncthreads();
        int wid = t >> 6, l = t & 63, lr = l & 15, lg = l >> 4;
        f32x4 acc[4][2];
        #pragma unroll
        for (int r = 0; r < 4; ++r) { acc[r][0] = (f32x4){0,0,0,0}; acc[r][1] = (f32x4){0,0,0,0}; }
        #pragma unroll 3
        for (int ks = 0; ks < 15; ++ks) {
            short8 a0 = *(const short8*)(kf + ((size_t)(ks*2+0)*64 + l)*8);
            short8 a1 = *(const short8*)(kf + ((size_t)(ks*2+1)*64 + l)*8);
            int koff = ks*32 + lg*8;
            int cx = koff / 160, rem = koff - cx*160;
            int u = rem >> 4, v0 = rem & 15;
            int w = lr + v0;
            int abase = (w & 7)*225 + cx*75 + (w >> 3);
            #pragma unroll
            for (int r = 0; r < 4; ++r) {
                int xrow = wid*4 + r + u;
                short8 bf = *(const short8*)(xcopy + (size_t)(abase + xrow*3)*8);
                acc[r][0] = __builtin_amdgcn_mfma_f32_16x16x32_bf16(a0, bf, acc[r][0], 0, 0, 0);
                acc[r][1] = __builtin_amdgcn_mfma_f32_16x16x32_bf16(a1, bf, acc[r][1], 0, 0, 0);
            }
        }
        // D: col(n=pixel)=lr, row(m=cy)=lg*4+rr (+16*half)
        int jcol = j0 + lr;
        bool jv = jcol < 55;
        #pragma unroll
        for (int r = 0; r < 4; ++r) {
            int ir = i0 + wid*4 + r;
            if (ir >= 55) continue;
            #pragma unroll
            for (int half = 0; half < 2; ++half) {
                #pragma unroll
                for (int rr = 0; rr < 4; ++rr) {
                    int cy = half*16 + lg*4 + rr;
                    if (jv) cxb[(size_t)b*K_FEAT + cy*K_P + ir*55 + jcol] = acc[r][half][rr];
                }
            }
        }
    } else {
        // ---------------- gemm1 (MFMA, k-split partials) ----------------
        int g = bid - 512;                  // 220 = 4 x 55
        int bx = g & 3, by = g >> 2;
        int wid = t >> 6, l = t & 63;
        int lr = l & 15, lg = l >> 4;
        int zi0 = bx*64 + wid*16;
        int k0  = by*1760;
        const short* Ap  = Wb  + (size_t)(zi0 + lr)*K_FEAT + k0 + lg*8;
        const short* Bp0 = fyb + (size_t)(lr)*K_FEAT      + k0 + lg*8;
        const short* Bp1 = fyb + (size_t)(16 + lr)*K_FEAT + k0 + lg*8;
        f32x4 acc0 = {0.f,0.f,0.f,0.f}, acc1 = {0.f,0.f,0.f,0.f};
        #pragma unroll 5
        for (int k = 0; k < 55; ++k) {
            short8 a  = *(const short8*)(Ap  + k*32);
            short8 b0 = *(const short8*)(Bp0 + k*32);
            short8 b1 = *(const short8*)(Bp1 + k*32);
            acc0 = __builtin_amdgcn_mfma_f32_16x16x32_bf16(a, b0, acc0, 0, 0, 0);
            acc1 = __builtin_amdgcn_mfma_f32_16x16x32_bf16(a, b1, acc1, 0, 0, 0);
        }
        float* zp = zpart + (size_t)by*8192;
        #pragma unroll
        for (int r = 0; r < 4; ++r) {
            zp[(lr)*K_Z    + zi0 + lg*4 + r] = acc0[r];
            zp[(16+lr)*K_Z + zi0 + lg*4 + r] = acc1[r];
        }
    }
}

// ---------------------------------------------------------------- softmax over z slots (reduce 55 partials) -> bf16 fzb
__global__ __launch_bounds__(256) void fzk(const float* __restrict__ zpart,
                                           short* __restrict__ fzb) {
    __shared__ float sr[256];
    int b = blockIdx.x, t = threadIdx.x;
    float zv = 0.f;
    #pragma unroll 5
    for (int p = 0; p < K_NSPLIT; ++p) zv += zpart[(size_t)p*8192 + b*K_Z + t];
    float v = 7.0f * zv;
    sr[t] = v; __syncthreads();
    for (int off = 128; off > 0; off >>= 1) {
        if (t < off) sr[t] = fmaxf(sr[t], sr[t+off]);
        __syncthreads();
    }
    float m = sr[0];
    __syncthreads();
    float e = __expf(v - m);
    sr[t] = e; __syncthreads();
    for (int off = 128; off > 0; off >>= 1) {
        if (t < off) sr[t] += sr[t+off];
        __syncthreads();
    }
    float s = sr[0];
    fzb[b*K_Z + t] = f2bf(e / s);
}

// ---------------------------------------------------------------- GEMM2 (MFMA) + y update
__global__ __launch_bounds__(256) void gemm2_mfma(const short* __restrict__ Wg2,
                                                  const short* __restrict__ fzb,
                                                  const float* __restrict__ cxb,
                                                  float* __restrict__ y) {
    int t = threadIdx.x;
    int wid = t >> 6, l = t & 63;
    int lr = l & 15, lg = l >> 4;
    int f0 = blockIdx.x*128 + wid*32;
    if (f0 >= K_FEAT) return;
    const short* A0 = fzb + (size_t)(lr)*K_Z      + lg*8;
    const short* A1 = fzb + (size_t)(16 + lr)*K_Z + lg*8;
    short8 af0[8], af1[8];
    #pragma unroll
    for (int k = 0; k < 8; ++k) {
        af0[k] = *(const short8*)(A0 + k*32);
        af1[k] = *(const short8*)(A1 + k*32);
    }
    f32x4 acc[2][2] = {{{0.f,0.f,0.f,0.f},{0.f,0.f,0.f,0.f}},
                       {{0.f,0.f,0.f,0.f},{0.f,0.f,0.f,0.f}}};
    #pragma unroll
    for (int nt = 0; nt < 2; ++nt) {
        int f1 = f0 + nt*16;
        #pragma unroll
        for (int k = 0; k < 8; ++k) {
            const short* bp = Wg2 + ((size_t)(k*4 + lg)*K_FEAT + f1 + lr)*8;
            short8 b = *(const short8*)bp;
            acc[0][nt] = __builtin_amdgcn_mfma_f32_16x16x32_bf16(af0[k], b, acc[0][nt], 0, 0, 0);
            acc[1][nt] = __builtin_amdgcn_mfma_f32_16x16x32_bf16(af1[k], b, acc[1][nt], 0, 0, 0);
        }
    }
    #pragma unroll
    for (int mt = 0; mt < 2; ++mt) {
        #pragma unroll
        for (int nt = 0; nt < 2; ++nt) {
            #pragma unroll
            for (int r = 0; r < 4; ++r) {
                int bb = mt*16 + lg*4 + r;
                size_t idx = (size_t)bb*K_FEAT + f0 + nt*16 + lr;
                y[idx] = 0.5f*(y[idx] + cxb[idx] + acc[mt][nt][r]);
            }
        }
    }
}

// ---------------------------------------------------------------- dual channel softmax:
// y -> syb (beta=1, bf16, [b][pixel][cy] packed) + fyb (beta=3, bf16, [b][cy][pixel])
__global__ __launch_bounds__(256) void softmax_dual(const float* __restrict__ y,
                                                    short* __restrict__ syb,
                                                    short* __restrict__ fyb) {
    int tid = blockIdx.x*256 + threadIdx.x;
    if (tid >= K_B*K_P) return;
    int b = tid / K_P, p = tid - b*K_P;
    const float* ip = y + (size_t)b*K_FEAT + p;
    float v[32];
    #pragma unroll
    for (int c = 0; c < 32; ++c) v[c] = ip[c*K_P];
    float m = v[0];
    #pragma unroll
    for (int c = 1; c < 32; ++c) m = fmaxf(m, v[c]);
    float e1[32];
    float s1 = 0.f, s3 = 0.f;
    #pragma unroll
    for (int c = 0; c < 32; ++c) {
        float d = v[c] - m;
        float a1 = __expf(d);
        float a3 = __expf(3.0f*d);
        e1[c] = a1; v[c] = a3;
        s1 += a1; s3 += a3;
    }
    float i1 = 1.0f/s1, i3 = 1.0f/s3;
    short* fp = fyb + (size_t)b*K_FEAT + p;
    #pragma unroll
    for (int c = 0; c < 32; ++c) fp[c*K_P] = f2bf(v[c]*i3);
    short8 o[4];
    #pragma unroll
    for (int g = 0; g < 4; ++g)
        #pragma unroll
        for (int j = 0; j < 8; ++j) o[g][j] = f2bf(e1[g*8+j]*i1);
    short* sp = syb + (size_t)tid*32;
    *(short8*)(sp)      = o[0];
    *(short8*)(sp + 8)  = o[1];
    *(short8*)(sp + 16) = o[2];
    *(short8*)(sp + 24) = o[3];
}

// ---------------------------------------------------------------- convT MFMA: x = 0.9x + 0.1*conv_transpose(sy)
// block = 16x32 output pixels; per-tap GEMM D[m=cx][n=16 px] += A[cx][cy] B[cy][px], 100 taps in acc
__global__ __launch_bounds__(256) void convT_mfma(const short* __restrict__ syb,
                                                  const short* __restrict__ KfragT,
                                                  float* __restrict__ x) {
    __shared__ __align__(16) short syt[25*41*32];   // 65600 B: [row][col][cy]
    int t = threadIdx.x;
    int tile = blockIdx.x;            // 0..7
    int b = blockIdx.y;
    int p0 = (tile >> 1) * 16, q0 = (tile & 1) * 32;
    for (int e = t; e < 1025; e += 256) {
        int row = e / 41, col = e - row*41;
        int gr = p0 - 9 + row, gc = q0 - 9 + col;
        short8 z = {0,0,0,0,0,0,0,0};
        short8 v0 = z, v1 = z, v2 = z, v3 = z;
        if (gr >= 0 && gr < 55 && gc >= 0 && gc < 55) {
            const short* sp = syb + ((size_t)b*K_P + gr*55 + gc) * 32;
            v0 = *(const short8*)(sp);
            v1 = *(const short8*)(sp + 8);
            v2 = *(const short8*)(sp + 16);
            v3 = *(const short8*)(sp + 24);
        }
        short* dp = syt + (size_t)e * 32;
        *(short8*)(dp)      = v0;
        *(short8*)(dp + 8)  = v1;
        *(short8*)(dp + 16) = v2;
        *(short8*)(dp + 24) = v3;
    }
    __syncthreads();
    int wid = t >> 6, l = t & 63, lr = l & 15, lg = l >> 4;
    f32x4 acc[4][2];
    #pragma unroll
    for (int r = 0; r < 4; ++r) { acc[r][0] = (f32x4){0,0,0,0}; acc[r][1] = (f32x4){0,0,0,0}; }
    const short* kfp = KfragT + (size_t)l * 8;
    for (int u = 0; u < 10; ++u) {
        #pragma unroll 5
        for (int v = 0; v < 10; ++v) {
            short8 a = *(const short8*)(kfp + (size_t)(u*10 + v)*512);
            #pragma unroll
            for (int r = 0; r < 4; ++r) {
                int rowlds = wid*4 + r + u;
                const short* bp = syt + ((size_t)(rowlds*41 + v + lr)*32 + lg*8);
                short8 b0 = *(const short8*)bp;
                short8 b1 = *(const short8*)(bp + 16*32);
                acc[r][0] = __builtin_amdgcn_mfma_f32_16x16x32_bf16(a, b0, acc[r][0], 0, 0, 0);
                acc[r][1] = __builtin_amdgcn_mfma_f32_16x16x32_bf16(a, b1, acc[r][1], 0, 0, 0);
            }
        }
    }
    // D: col(n=pixel)=lr, row(m=cx)=lg*4+rr -> only lg==0, rr<3 meaningful
    if (lg == 0) {
        #pragma unroll
        for (int r = 0; r < 4; ++r) {
            int p = p0 + wid*4 + r;
            #pragma unroll
            for (int ct = 0; ct < 2; ++ct) {
                int q = q0 + ct*16 + lr;
                #pragma unroll
                for (int c = 0; c < 3; ++c) {
                    float* xp = x + (size_t)b*K_XN + c*4096 + p*64 + q;
                    *xp = 0.9f*(*xp) + 0.1f*acc[r][ct][c];
                }
            }
        }
    }
}

// ----------------------------------------------------------------
extern "C" void kernel_launch(void* const* d_in, const int* in_sizes, int n_in,
                              void* d_out, int out_size, void* d_ws, size_t ws_size,
                              hipStream_t stream) {
    const float* xin = (const float*)d_in[0];   // [32,3,64,64]
    const float* Kw  = (const float*)d_in[1];   // [32,3,10,10]
    const float* W   = (const float*)d_in[2];   // [256,96800]
    float* x = (float*)d_out;                   // x state lives in d_out

    float* ws     = (float*)d_ws;
    float* y      = ws;                         // 3,097,600 f
    float* cxb    = y     + 3097600;            // 3,097,600 f
    float* zpart  = cxb   + 3097600;            // 450,560 f
    short* fyb    = (short*)(zpart + 450560);   // 3,097,600 s
    short* fzb    = fyb   + 3097600;            // 8,192 s
    short* Wb     = fzb   + 8192;               // 24,780,800 s
    short* Wg2    = Wb    + 24780800;           // 24,780,800 s
    short* syb    = Wg2   + 24780800;           // 3,097,600 s
    short* KfragT = syb   + 3097600;            // 51,200 s
    short* Kfrag2 = KfragT+ 51200;              // 15,360 s

    hipMemcpyAsync(x, xin, (size_t)K_B*K_XN*sizeof(float), hipMemcpyDeviceToDevice, stream);
    hipMemsetAsync(y, 0, (size_t)3097600*sizeof(float), stream);
    prep_frags<<<33, 256, 0, stream>>>(Kw, KfragT, Kfrag2);
    w_to_bf16<<<12100, 256, 0, stream>>>(W, Wb);
    w_to_g2<<<dim3(379,32), 256, 0, stream>>>(W, Wg2);
    fyb_fill<<<1513, 256, 0, stream>>>(fyb);

    for (int s = 0; s < 30; ++s) {
        fused_A<<<732, 256, 0, stream>>>(x, cxb, Wb, fyb, zpart, Kfrag2);
        fzk<<<32, 256, 0, stream>>>(zpart, fzb);
        gemm2_mfma<<<757, 256, 0, stream>>>(Wg2, fzb, cxb, y);
        softmax_dual<<<379, 256, 0, stream>>>(y, syb, fyb);
        convT_mfma<<<dim3(8,32), 256, 0, stream>>>(syb, KfragT, x);
    }
}

// Round 5
// 2828.981 us; speedup vs baseline: 3.1570x; 1.1333x over previous
//
#include <hip/hip_runtime.h>

#define K_B    32
#define K_CXC  3
#define K_XS   64
#define K_CY   32
#define K_M    55
#define K_Z    256
#define K_P    (K_M*K_M)          // 3025
#define K_FEAT (K_CY*K_P)         // 96800
#define K_XN   (K_CXC*K_XS*K_XS)  // 12288 per batch
#define K_NSPLIT 55               // gemm1 k-splits

typedef __attribute__((ext_vector_type(8))) short short8;
typedef __attribute__((ext_vector_type(4))) float f32x4;

__device__ __forceinline__ short f2bf(float f) {
    unsigned u = __builtin_bit_cast(unsigned, f);
    unsigned r = (u + 0x7FFFu + ((u >> 16) & 1u)) >> 16;
    return (short)r;
}

// ---------------------------------------------------------------- once: W -> Wbp[zi][p*32+cy] bf16 (gemm1 A, permuted F)
__global__ __launch_bounds__(256) void w_perm1(const float* __restrict__ W,
                                               short* __restrict__ Wbp) {
    int o = blockIdx.x*256 + threadIdx.x;        // 3,097,600 chunks of 8
    int zi = o / 12100, c = o - zi*12100;
    int p = c >> 2, cyg = c & 3;
    const float* wp = W + (size_t)zi*K_FEAT + p;
    short8 v;
    #pragma unroll
    for (int j = 0; j < 8; ++j) v[j] = f2bf(wp[(size_t)(cyg*8 + j)*K_P]);
    *(short8*)(Wbp + (size_t)o*8) = v;
}

// ---------------------------------------------------------------- once: W -> Wg2p[zb][F][8] bf16 (gemm2 B, permuted F)
__global__ __launch_bounds__(256) void w_perm2(const float* __restrict__ W,
                                               short* __restrict__ Wg2p) {
    int F = blockIdx.x*256 + threadIdx.x;
    if (F >= K_FEAT) return;
    int zb = blockIdx.y;
    int cy = F & 31, p = F >> 5;
    short8 o;
    #pragma unroll
    for (int j = 0; j < 8; ++j)
        o[j] = f2bf(W[(size_t)(zb*8 + j)*K_FEAT + cy*K_P + p]);
    *(short8*)(Wg2p + ((size_t)zb*K_FEAT + F)*8) = o;
}

// ---------------------------------------------------------------- once: per-lane MFMA kernel-fragment tables
__global__ __launch_bounds__(256) void prep_frags(const float* __restrict__ Kw,
                                                  short* __restrict__ KfragT,
                                                  short* __restrict__ Kfrag2) {
    int e = blockIdx.x*256 + threadIdx.x;
    if (e < 6400) {
        int uv = e >> 6, l = e & 63;
        int u = uv / 10, v = uv - u*10;
        int lr = l & 15, lg = l >> 4;
        short8 o;
        #pragma unroll
        for (int j = 0; j < 8; ++j) {
            int cy = lg*8 + j;
            o[j] = (lr < 3) ? f2bf(Kw[cy*300 + lr*100 + (9-u)*10 + (9-v)]) : (short)0;
        }
        *(short8*)(KfragT + (size_t)e*8) = o;
    } else if (e < 6400 + 1920) {
        int e2 = e - 6400;
        int kn = e2 >> 6, l = e2 & 63;
        int ks = kn >> 1, nt = kn & 1;
        int lr = l & 15, lg = l >> 4;
        short8 o;
        #pragma unroll
        for (int j = 0; j < 8; ++j) {
            int k = ks*32 + lg*8 + j;
            int cx = k / 160, rem = k - cx*160;
            int u = rem >> 4, v = rem & 15;
            o[j] = (v < 10) ? f2bf(Kw[(lr + nt*16)*300 + cx*100 + u*10 + v]) : (short)0;
        }
        *(short8*)(Kfrag2 + (size_t)e2*8) = o;
    }
}

// ---------------------------------------------------------------- once: fyb = softmax(0) = 1/32
__global__ __launch_bounds__(256) void fyb_fill(short* __restrict__ fyb) {
    size_t i = ((size_t)blockIdx.x*256 + threadIdx.x) * 8;
    if (i >= (size_t)K_B*K_FEAT) return;
    short8 o = {0x3D00,0x3D00,0x3D00,0x3D00,0x3D00,0x3D00,0x3D00,0x3D00};
    *(short8*)(fyb + i) = o;
}

// ---------------------------------------------------------------- fused A: conv_fwd MFMA (0..511) + gemm1 (512..731)
// conv writes cxb in [b][p][cy]; gemm1 uses permuted Wbp/fyb (k-order = F).
__global__ __launch_bounds__(256) void fused_A(const float* __restrict__ x,
                                               float* __restrict__ cxb,
                                               const short* __restrict__ Wbp,
                                               const short* __restrict__ fyb,
                                               float* __restrict__ zpart,
                                               const short* __restrict__ Kfrag2) {
    __shared__ __align__(16) short xcopy[14400];  // 1800 x 16B shift-replicated x tile
    int bid = blockIdx.x;
    int t = threadIdx.x;
    if (bid < 512) {
        // ---------------- conv_fwd ----------------
        int b = bid >> 4, tile = bid & 15;
        int i0 = (tile >> 2) * 16, j0 = (tile & 3) * 16;
        const float* xb = x + (size_t)b*K_XN;
        for (int e = t; e < 1800; e += 256) {
            int s = e / 225, rem = e - s*225;
            int cx = rem / 75, r2 = rem - cx*75;
            int row = r2 / 3, i16 = r2 - row*3;
            int gr = i0 + row;
            int gc0 = j0 + i16*8 + s;
            const float* xp = xb + cx*4096 + gr*64;
            short8 o;
            #pragma unroll
            for (int j = 0; j < 8; ++j) {
                int gc = gc0 + j;
                float v = (gr < 64 && gc < 64) ? xp[gc] : 0.f;
                o[j] = f2bf(v);
            }
            *(short8*)(xcopy + (size_t)e*8) = o;
        }
        __syncthreads();
        int wid = t >> 6, l = t & 63, lr = l & 15, lg = l >> 4;
        f32x4 acc[4][2];
        #pragma unroll
        for (int r = 0; r < 4; ++r) { acc[r][0] = (f32x4){0,0,0,0}; acc[r][1] = (f32x4){0,0,0,0}; }
        #pragma unroll 3
        for (int ks = 0; ks < 15; ++ks) {
            short8 a0 = *(const short8*)(Kfrag2 + ((size_t)(ks*2+0)*64 + l)*8);
            short8 a1 = *(const short8*)(Kfrag2 + ((size_t)(ks*2+1)*64 + l)*8);
            int koff = ks*32 + lg*8;
            int cx = koff / 160, rem = koff - cx*160;
            int u = rem >> 4, v0 = rem & 15;
            int w = lr + v0;
            int abase = (w & 7)*225 + cx*75 + (w >> 3);
            #pragma unroll
            for (int r = 0; r < 4; ++r) {
                int xrow = wid*4 + r + u;
                short8 bf = *(const short8*)(xcopy + (size_t)(abase + xrow*3)*8);
                acc[r][0] = __builtin_amdgcn_mfma_f32_16x16x32_bf16(a0, bf, acc[r][0], 0, 0, 0);
                acc[r][1] = __builtin_amdgcn_mfma_f32_16x16x32_bf16(a1, bf, acc[r][1], 0, 0, 0);
            }
        }
        int jcol = j0 + lr;
        bool jv = jcol < 55;
        #pragma unroll
        for (int r = 0; r < 4; ++r) {
            int ir = i0 + wid*4 + r;
            if (ir >= 55 || !jv) continue;
            size_t base = (size_t)b*K_FEAT + (size_t)(ir*55 + jcol)*32 + lg*4;
            *(f32x4*)&cxb[base]      = acc[r][0];
            *(f32x4*)&cxb[base + 16] = acc[r][1];
        }
    } else {
        // ---------------- gemm1 (MFMA, k-split partials, permuted F) ----------------
        int g = bid - 512;                  // 220 = 4 x 55
        int bx = g & 3, by = g >> 2;
        int wid = t >> 6, l = t & 63;
        int lr = l & 15, lg = l >> 4;
        int zi0 = bx*64 + wid*16;
        int k0  = by*1760;
        const short* Ap  = Wbp + (size_t)(zi0 + lr)*K_FEAT + k0 + lg*8;
        const short* Bp0 = fyb + (size_t)(lr)*K_FEAT      + k0 + lg*8;
        const short* Bp1 = fyb + (size_t)(16 + lr)*K_FEAT + k0 + lg*8;
        f32x4 acc0 = {0.f,0.f,0.f,0.f}, acc1 = {0.f,0.f,0.f,0.f};
        #pragma unroll 5
        for (int k = 0; k < 55; ++k) {
            short8 a  = *(const short8*)(Ap  + k*32);
            short8 b0 = *(const short8*)(Bp0 + k*32);
            short8 b1 = *(const short8*)(Bp1 + k*32);
            acc0 = __builtin_amdgcn_mfma_f32_16x16x32_bf16(a, b0, acc0, 0, 0, 0);
            acc1 = __builtin_amdgcn_mfma_f32_16x16x32_bf16(a, b1, acc1, 0, 0, 0);
        }
        float* zp = zpart + (size_t)by*8192;
        #pragma unroll
        for (int r = 0; r < 4; ++r) {
            zp[(lr)*K_Z    + zi0 + lg*4 + r] = acc0[r];
            zp[(16+lr)*K_Z + zi0 + lg*4 + r] = acc1[r];
        }
    }
}

// ---------------------------------------------------------------- softmax over z (reduce 55 partials) -> bf16 fzb
__global__ __launch_bounds__(256) void fzk(const float* __restrict__ zpart,
                                           short* __restrict__ fzb) {
    __shared__ float sr[256];
    int b = blockIdx.x, t = threadIdx.x;
    float zv = 0.f;
    #pragma unroll 5
    for (int p = 0; p < K_NSPLIT; ++p) zv += zpart[(size_t)p*8192 + b*K_Z + t];
    float v = 7.0f * zv;
    sr[t] = v; __syncthreads();
    for (int off = 128; off > 0; off >>= 1) {
        if (t < off) sr[t] = fmaxf(sr[t], sr[t+off]);
        __syncthreads();
    }
    float m = sr[0];
    __syncthreads();
    float e = __expf(v - m);
    sr[t] = e; __syncthreads();
    for (int off = 128; off > 0; off >>= 1) {
        if (t < off) sr[t] += sr[t+off];
        __syncthreads();
    }
    float s = sr[0];
    fzb[b*K_Z + t] = f2bf(e / s);
}

// ---------------------------------------------------------------- GEMM2 (MFMA) + y update + fused channel softmax
// wave covers 1 pixel x 32 cy per nt-pair; softmax over cy via 16-lane shfl reduce.
__global__ __launch_bounds__(256) void gemm2_sm(const short* __restrict__ Wg2p,
                                                const short* __restrict__ fzb,
                                                const float* __restrict__ cxb,
                                                float* __restrict__ y,
                                                short* __restrict__ syb,
                                                short* __restrict__ fyb) {
    int t = threadIdx.x;
    int wid = t >> 6, l = t & 63;
    int lr = l & 15, lg = l >> 4;
    int f0 = blockIdx.x*128 + wid*32;
    int p = f0 >> 5;
    if (p >= K_P) return;
    const short* A0 = fzb + (size_t)(lr)*K_Z      + lg*8;
    const short* A1 = fzb + (size_t)(16 + lr)*K_Z + lg*8;
    short8 af0[8], af1[8];
    #pragma unroll
    for (int k = 0; k < 8; ++k) {
        af0[k] = *(const short8*)(A0 + k*32);
        af1[k] = *(const short8*)(A1 + k*32);
    }
    f32x4 acc[2][2] = {{{0.f,0.f,0.f,0.f},{0.f,0.f,0.f,0.f}},
                       {{0.f,0.f,0.f,0.f},{0.f,0.f,0.f,0.f}}};
    #pragma unroll
    for (int nt = 0; nt < 2; ++nt) {
        #pragma unroll
        for (int k = 0; k < 8; ++k) {
            const short* bp = Wg2p + ((size_t)(k*4 + lg)*K_FEAT + f0 + nt*16 + lr)*8;
            short8 b = *(const short8*)bp;
            acc[0][nt] = __builtin_amdgcn_mfma_f32_16x16x32_bf16(af0[k], b, acc[0][nt], 0, 0, 0);
            acc[1][nt] = __builtin_amdgcn_mfma_f32_16x16x32_bf16(af1[k], b, acc[1][nt], 0, 0, 0);
        }
    }
    // epilogue: per row bb, softmax over 32 cy (2 vals/lane x 16 lanes)
    #pragma unroll
    for (int mt = 0; mt < 2; ++mt) {
        #pragma unroll
        for (int r = 0; r < 4; ++r) {
            int bb = mt*16 + lg*4 + r;
            size_t i0a = (size_t)bb*K_FEAT + f0 + lr;
            size_t i1a = i0a + 16;
            float v0 = 0.5f*(y[i0a] + cxb[i0a] + acc[mt][0][r]);
            float v1 = 0.5f*(y[i1a] + cxb[i1a] + acc[mt][1][r]);
            float mx = fmaxf(v0, v1);
            #pragma unroll
            for (int m = 1; m <= 8; m <<= 1) mx = fmaxf(mx, __shfl_xor(mx, m));
            float d0 = v0 - mx, d1 = v1 - mx;
            float e10 = __expf(d0),      e11 = __expf(d1);
            float e30 = __expf(3.0f*d0), e31 = __expf(3.0f*d1);
            float s1 = e10 + e11, s3 = e30 + e31;
            #pragma unroll
            for (int m = 1; m <= 8; m <<= 1) { s1 += __shfl_xor(s1, m); s3 += __shfl_xor(s3, m); }
            float i1 = 1.0f/s1, i3 = 1.0f/s3;
            y[i0a] = v0; y[i1a] = v1;
            syb[i0a] = f2bf(e10*i1); syb[i1a] = f2bf(e11*i1);
            fyb[i0a] = f2bf(e30*i3); fyb[i1a] = f2bf(e31*i3);
        }
    }
}

// ---------------------------------------------------------------- convT MFMA: x = 0.9x + 0.1*conv_transpose(sy)
__global__ __launch_bounds__(256) void convT_mfma(const short* __restrict__ syb,
                                                  const short* __restrict__ KfragT,
                                                  float* __restrict__ x) {
    __shared__ __align__(16) short syt[25*41*32];   // 65600 B: [row][col][cy]
    int t = threadIdx.x;
    int tile = blockIdx.x;            // 0..7
    int b = blockIdx.y;
    int p0 = (tile >> 1) * 16, q0 = (tile & 1) * 32;
    for (int e = t; e < 1025; e += 256) {
        int row = e / 41, col = e - row*41;
        int gr = p0 - 9 + row, gc = q0 - 9 + col;
        short8 z = {0,0,0,0,0,0,0,0};
        short8 v0 = z, v1 = z, v2 = z, v3 = z;
        if (gr >= 0 && gr < 55 && gc >= 0 && gc < 55) {
            const short* sp = syb + ((size_t)b*K_P + gr*55 + gc) * 32;
            v0 = *(const short8*)(sp);
            v1 = *(const short8*)(sp + 8);
            v2 = *(const short8*)(sp + 16);
            v3 = *(const short8*)(sp + 24);
        }
        short* dp = syt + (size_t)e * 32;
        *(short8*)(dp)      = v0;
        *(short8*)(dp + 8)  = v1;
        *(short8*)(dp + 16) = v2;
        *(short8*)(dp + 24) = v3;
    }
    __syncthreads();
    int wid = t >> 6, l = t & 63, lr = l & 15, lg = l >> 4;
    f32x4 acc[4][2];
    #pragma unroll
    for (int r = 0; r < 4; ++r) { acc[r][0] = (f32x4){0,0,0,0}; acc[r][1] = (f32x4){0,0,0,0}; }
    const short* kfp = KfragT + (size_t)l * 8;
    for (int u = 0; u < 10; ++u) {
        #pragma unroll 5
        for (int v = 0; v < 10; ++v) {
            short8 a = *(const short8*)(kfp + (size_t)(u*10 + v)*512);
            #pragma unroll
            for (int r = 0; r < 4; ++r) {
                int rowlds = wid*4 + r + u;
                const short* bp = syt + ((size_t)(rowlds*41 + v + lr)*32 + lg*8);
                short8 b0 = *(const short8*)bp;
                short8 b1 = *(const short8*)(bp + 16*32);
                acc[r][0] = __builtin_amdgcn_mfma_f32_16x16x32_bf16(a, b0, acc[r][0], 0, 0, 0);
                acc[r][1] = __builtin_amdgcn_mfma_f32_16x16x32_bf16(a, b1, acc[r][1], 0, 0, 0);
            }
        }
    }
    if (lg == 0) {
        #pragma unroll
        for (int r = 0; r < 4; ++r) {
            int p = p0 + wid*4 + r;
            #pragma unroll
            for (int ct = 0; ct < 2; ++ct) {
                int q = q0 + ct*16 + lr;
                #pragma unroll
                for (int c = 0; c < 3; ++c) {
                    float* xp = x + (size_t)b*K_XN + c*4096 + p*64 + q;
                    *xp = 0.9f*(*xp) + 0.1f*acc[r][ct][c];
                }
            }
        }
    }
}

// ----------------------------------------------------------------
extern "C" void kernel_launch(void* const* d_in, const int* in_sizes, int n_in,
                              void* d_out, int out_size, void* d_ws, size_t ws_size,
                              hipStream_t stream) {
    const float* xin = (const float*)d_in[0];   // [32,3,64,64]
    const float* Kw  = (const float*)d_in[1];   // [32,3,10,10]
    const float* W   = (const float*)d_in[2];   // [256,96800]
    float* x = (float*)d_out;                   // x state lives in d_out

    float* ws     = (float*)d_ws;
    float* y      = ws;                         // 3,097,600 f   [b][p*32+cy]
    float* cxb    = y     + 3097600;            // 3,097,600 f   [b][p*32+cy]
    float* zpart  = cxb   + 3097600;            // 450,560 f
    short* fyb    = (short*)(zpart + 450560);   // 3,097,600 s   [b][p*32+cy]
    short* fzb    = fyb   + 3097600;            // 8,192 s
    short* Wbp    = fzb   + 8192;               // 24,780,800 s
    short* Wg2p   = Wbp   + 24780800;           // 24,780,800 s
    short* syb    = Wg2p  + 24780800;           // 3,097,600 s   [b][p*32+cy]
    short* KfragT = syb   + 3097600;            // 51,200 s
    short* Kfrag2 = KfragT+ 51200;              // 15,360 s

    hipMemcpyAsync(x, xin, (size_t)K_B*K_XN*sizeof(float), hipMemcpyDeviceToDevice, stream);
    hipMemsetAsync(y, 0, (size_t)3097600*sizeof(float), stream);
    prep_frags<<<33, 256, 0, stream>>>(Kw, KfragT, Kfrag2);
    w_perm1<<<12100, 256, 0, stream>>>(W, Wbp);
    w_perm2<<<dim3(379,32), 256, 0, stream>>>(W, Wg2p);
    fyb_fill<<<1513, 256, 0, stream>>>(fyb);

    for (int s = 0; s < 30; ++s) {
        fused_A<<<732, 256, 0, stream>>>(x, cxb, Wbp, fyb, zpart, Kfrag2);
        fzk<<<32, 256, 0, stream>>>(zpart, fzb);
        gemm2_sm<<<757, 256, 0, stream>>>(Wg2p, fzb, cxb, y, syb, fyb);
        convT_mfma<<<dim3(8,32), 256, 0, stream>>>(syb, KfragT, x);
    }
}

// Round 6
// 2663.986 us; speedup vs baseline: 3.3526x; 1.0619x over previous
//
#include <hip/hip_runtime.h>

#define K_B    32
#define K_CXC  3
#define K_XS   64
#define K_CY   32
#define K_M    55
#define K_Z    256
#define K_P    (K_M*K_M)          // 3025
#define K_FEAT (K_CY*K_P)         // 96800
#define K_XN   (K_CXC*K_XS*K_XS)  // 12288 per batch
#define K_NSPLIT 55               // gemm1 k-splits

typedef __attribute__((ext_vector_type(8))) short short8;
typedef __attribute__((ext_vector_type(4))) float f32x4;

__device__ __forceinline__ short f2bf(float f) {
    unsigned u = __builtin_bit_cast(unsigned, f);
    unsigned r = (u + 0x7FFFu + ((u >> 16) & 1u)) >> 16;
    return (short)r;
}

// ---------------------------------------------------------------- once: W -> Wbp[zi][p*32+cy] bf16 + zrow[zi]=rowsum
// grid (12 p-tiles, 256 zi). Coalesced reads, padded-LDS transpose, coalesced writes.
__global__ __launch_bounds__(256) void w_perm1_t(const float* __restrict__ W,
                                                 short* __restrict__ Wbp,
                                                 float* __restrict__ zrow) {
    __shared__ short ldt[256*33];
    int t = threadIdx.x;
    int pt = blockIdx.x, zi = blockIdx.y;
    int p = pt*256 + t;
    bool pv = p < K_P;
    const float* wz = W + (size_t)zi*K_FEAT;
    float sum = 0.f;
    #pragma unroll 8
    for (int cy = 0; cy < 32; ++cy) {
        float v = pv ? wz[cy*K_P + p] : 0.f;
        sum += v;
        ldt[t*33 + cy] = f2bf(v);
    }
    // zrow accumulation (fp32 exact row-sum of W)
    #pragma unroll
    for (int m = 1; m < 64; m <<= 1) sum += __shfl_xor(sum, m);
    if ((t & 63) == 0) atomicAdd(&zrow[zi], sum);
    __syncthreads();
    if (pv) {
        short8 o[4];
        #pragma unroll
        for (int g = 0; g < 4; ++g)
            #pragma unroll
            for (int j = 0; j < 8; ++j) o[g][j] = ldt[t*33 + g*8 + j];
        short* dp = Wbp + (size_t)zi*K_FEAT + (size_t)p*32;
        *(short8*)(dp)      = o[0];
        *(short8*)(dp + 8)  = o[1];
        *(short8*)(dp + 16) = o[2];
        *(short8*)(dp + 24) = o[3];
    }
}

// ---------------------------------------------------------------- once: W -> Wg2p[zb][p*32+cy][8] bf16
// grid (12 p-tiles, 32 zb). Coalesced reads, register pack, short8 stores (L2-merged).
__global__ __launch_bounds__(256) void w_perm2_r(const float* __restrict__ W,
                                                 short* __restrict__ Wg2p) {
    int t = threadIdx.x;
    int pt = blockIdx.x, zb = blockIdx.y;
    int p = pt*256 + t;
    if (p >= K_P) return;
    #pragma unroll 4
    for (int cy = 0; cy < 32; ++cy) {
        short8 o;
        #pragma unroll
        for (int j = 0; j < 8; ++j)
            o[j] = f2bf(W[(size_t)(zb*8 + j)*K_FEAT + cy*K_P + p]);
        *(short8*)(Wg2p + ((size_t)zb*K_FEAT + (size_t)p*32 + cy)*8) = o;
    }
}

// ---------------------------------------------------------------- once: per-lane MFMA kernel-fragment tables
__global__ __launch_bounds__(256) void prep_frags(const float* __restrict__ Kw,
                                                  short* __restrict__ KfragT,
                                                  short* __restrict__ Kfrag2) {
    int e = blockIdx.x*256 + threadIdx.x;
    if (e < 6400) {
        int uv = e >> 6, l = e & 63;
        int u = uv / 10, v = uv - u*10;
        int lr = l & 15, lg = l >> 4;
        short8 o;
        #pragma unroll
        for (int j = 0; j < 8; ++j) {
            int cy = lg*8 + j;
            o[j] = (lr < 3) ? f2bf(Kw[cy*300 + lr*100 + (9-u)*10 + (9-v)]) : (short)0;
        }
        *(short8*)(KfragT + (size_t)e*8) = o;
    } else if (e < 6400 + 1920) {
        int e2 = e - 6400;
        int kn = e2 >> 6, l = e2 & 63;
        int ks = kn >> 1, nt = kn & 1;
        int lr = l & 15, lg = l >> 4;
        short8 o;
        #pragma unroll
        for (int j = 0; j < 8; ++j) {
            int k = ks*32 + lg*8 + j;
            int cx = k / 160, rem = k - cx*160;
            int u = rem >> 4, v = rem & 15;
            o[j] = (v < 10) ? f2bf(Kw[(lr + nt*16)*300 + cx*100 + u*10 + v]) : (short)0;
        }
        *(short8*)(Kfrag2 + (size_t)e2*8) = o;
    }
}

// ---------------------------------------------------------------- conv body (device fn, used by fused_A and conv_first)
__device__ __forceinline__ void conv_body(const float* __restrict__ x,
                                          float* __restrict__ cxb,
                                          const short* __restrict__ Kfrag2,
                                          int b, int tile, int t,
                                          short* xcopy, float* xraw) {
    int i0 = (tile >> 2) * 16, j0 = (tile & 3) * 16;
    const float* xb = x + (size_t)b*K_XN;
    // phase 1: raw fp32 tile, float4 coalesced
    for (int e = t; e < 600; e += 256) {
        int rowid = e >> 3, q = e & 7;
        int cx = rowid / 25, rr = rowid - cx*25;
        int gr = i0 + rr, gc = j0 + q*4;
        float4 v = {0.f,0.f,0.f,0.f};
        if (gr < 64 && gc < 64) v = *(const float4*)(xb + cx*4096 + gr*64 + gc);
        *(float4*)&xraw[(cx*25+rr)*32 + q*4] = v;
    }
    __syncthreads();
    // phase 2: build 8 shift-replicated bf16 copies from LDS
    for (int e = t; e < 1800; e += 256) {
        int s = e / 225, rem = e - s*225;
        int cx = rem / 75, r2 = rem - cx*75;
        int row = r2 / 3, i16 = r2 - row*3;
        const float* rp = &xraw[(cx*25+row)*32 + i16*8 + s];
        short8 o;
        #pragma unroll
        for (int j = 0; j < 8; ++j) o[j] = f2bf(rp[j]);
        *(short8*)(xcopy + (size_t)e*8) = o;
    }
    __syncthreads();
    int wid = t >> 6, l = t & 63, lr = l & 15, lg = l >> 4;
    f32x4 acc[4][2];
    #pragma unroll
    for (int r = 0; r < 4; ++r) { acc[r][0] = (f32x4){0,0,0,0}; acc[r][1] = (f32x4){0,0,0,0}; }
    #pragma unroll 3
    for (int ks = 0; ks < 15; ++ks) {
        short8 a0 = *(const short8*)(Kfrag2 + ((size_t)(ks*2+0)*64 + l)*8);
        short8 a1 = *(const short8*)(Kfrag2 + ((size_t)(ks*2+1)*64 + l)*8);
        int koff = ks*32 + lg*8;
        int cx = koff / 160, rem = koff - cx*160;
        int u = rem >> 4, v0 = rem & 15;
        int w = lr + v0;
        int abase = (w & 7)*225 + cx*75 + (w >> 3);
        #pragma unroll
        for (int r = 0; r < 4; ++r) {
            int xrow = wid*4 + r + u;
            short8 bf = *(const short8*)(xcopy + (size_t)(abase + xrow*3)*8);
            acc[r][0] = __builtin_amdgcn_mfma_f32_16x16x32_bf16(a0, bf, acc[r][0], 0, 0, 0);
            acc[r][1] = __builtin_amdgcn_mfma_f32_16x16x32_bf16(a1, bf, acc[r][1], 0, 0, 0);
        }
    }
    int jcol = j0 + lr;
    bool jv = jcol < 55;
    #pragma unroll
    for (int r = 0; r < 4; ++r) {
        int ir = i0 + wid*4 + r;
        if (ir >= 55 || !jv) continue;
        size_t base = (size_t)b*K_FEAT + (size_t)(ir*55 + jcol)*32 + lg*4;
        *(f32x4*)&cxb[base]      = acc[r][0];
        *(f32x4*)&cxb[base + 16] = acc[r][1];
    }
}

// ---------------------------------------------------------------- fused A: conv (0..511) + gemm1 (512..731)
__global__ __launch_bounds__(256) void fused_A(const float* __restrict__ x,
                                               float* __restrict__ cxb,
                                               const short* __restrict__ Wbp,
                                               const short* __restrict__ fyb,
                                               float* __restrict__ zpart,
                                               const short* __restrict__ Kfrag2) {
    __shared__ __align__(16) short xcopy[14400];
    __shared__ __align__(16) float xraw[2400];
    int bid = blockIdx.x;
    int t = threadIdx.x;
    if (bid < 512) {
        conv_body(x, cxb, Kfrag2, bid >> 4, bid & 15, t, xcopy, xraw);
    } else {
        int g = bid - 512;                  // 220 = 4 x 55
        int bx = g & 3, by = g >> 2;
        int wid = t >> 6, l = t & 63;
        int lr = l & 15, lg = l >> 4;
        int zi0 = bx*64 + wid*16;
        int k0  = by*1760;
        const short* Ap  = Wbp + (size_t)(zi0 + lr)*K_FEAT + k0 + lg*8;
        const short* Bp0 = fyb + (size_t)(lr)*K_FEAT      + k0 + lg*8;
        const short* Bp1 = fyb + (size_t)(16 + lr)*K_FEAT + k0 + lg*8;
        f32x4 acc0 = {0.f,0.f,0.f,0.f}, acc1 = {0.f,0.f,0.f,0.f};
        #pragma unroll 5
        for (int k = 0; k < 55; ++k) {
            short8 a  = *(const short8*)(Ap  + k*32);
            short8 b0 = *(const short8*)(Bp0 + k*32);
            short8 b1 = *(const short8*)(Bp1 + k*32);
            acc0 = __builtin_amdgcn_mfma_f32_16x16x32_bf16(a, b0, acc0, 0, 0, 0);
            acc1 = __builtin_amdgcn_mfma_f32_16x16x32_bf16(a, b1, acc1, 0, 0, 0);
        }
        float* zp = zpart + (size_t)by*8192;
        #pragma unroll
        for (int r = 0; r < 4; ++r) {
            zp[(lr)*K_Z    + zi0 + lg*4 + r] = acc0[r];
            zp[(16+lr)*K_Z + zi0 + lg*4 + r] = acc1[r];
        }
    }
}

// ---------------------------------------------------------------- step-0 conv-only
__global__ __launch_bounds__(256) void conv_first(const float* __restrict__ x,
                                                  float* __restrict__ cxb,
                                                  const short* __restrict__ Kfrag2) {
    __shared__ __align__(16) short xcopy[14400];
    __shared__ __align__(16) float xraw[2400];
    int bid = blockIdx.x;
    conv_body(x, cxb, Kfrag2, bid >> 4, bid & 15, threadIdx.x, xcopy, xraw);
}

// ---------------------------------------------------------------- softmax over z (reduce 55 partials) -> bf16 fzb
__global__ __launch_bounds__(256) void fzk(const float* __restrict__ zpart,
                                           short* __restrict__ fzb) {
    __shared__ float sr[256];
    int b = blockIdx.x, t = threadIdx.x;
    float zv = 0.f;
    #pragma unroll 5
    for (int p = 0; p < K_NSPLIT; ++p) zv += zpart[(size_t)p*8192 + b*K_Z + t];
    float v = 7.0f * zv;
    sr[t] = v; __syncthreads();
    for (int off = 128; off > 0; off >>= 1) {
        if (t < off) sr[t] = fmaxf(sr[t], sr[t+off]);
        __syncthreads();
    }
    float m = sr[0];
    __syncthreads();
    float e = __expf(v - m);
    sr[t] = e; __syncthreads();
    for (int off = 128; off > 0; off >>= 1) {
        if (t < off) sr[t] += sr[t+off];
        __syncthreads();
    }
    float s = sr[0];
    fzb[b*K_Z + t] = f2bf(e / s);
}

// ---------------------------------------------------------------- step-0 fz: z = zrow/32 (batch-independent, exact fp32)
__global__ __launch_bounds__(256) void fzk_first(const float* __restrict__ zrow,
                                                 short* __restrict__ fzb) {
    __shared__ float sr[256];
    int t = threadIdx.x;
    float v = 7.0f * zrow[t] * 0.03125f;
    sr[t] = v; __syncthreads();
    for (int off = 128; off > 0; off >>= 1) {
        if (t < off) sr[t] = fmaxf(sr[t], sr[t+off]);
        __syncthreads();
    }
    float m = sr[0];
    __syncthreads();
    float e = __expf(v - m);
    sr[t] = e; __syncthreads();
    for (int off = 128; off > 0; off >>= 1) {
        if (t < off) sr[t] += sr[t+off];
        __syncthreads();
    }
    float s = sr[0];
    short r = f2bf(e / s);
    #pragma unroll
    for (int b = 0; b < 32; ++b) fzb[b*K_Z + t] = r;
}

// ---------------------------------------------------------------- GEMM2 (MFMA) + y update + fused channel softmax
template<bool FIRST>
__global__ __launch_bounds__(256) void gemm2_sm(const short* __restrict__ Wg2p,
                                                const short* __restrict__ fzb,
                                                const float* __restrict__ cxb,
                                                float* __restrict__ y,
                                                short* __restrict__ syb,
                                                short* __restrict__ fyb) {
    int t = threadIdx.x;
    int wid = t >> 6, l = t & 63;
    int lr = l & 15, lg = l >> 4;
    int f0 = blockIdx.x*128 + wid*32;
    if (f0 >= K_FEAT) return;
    const short* A0 = fzb + (size_t)(lr)*K_Z      + lg*8;
    const short* A1 = fzb + (size_t)(16 + lr)*K_Z + lg*8;
    short8 af0[8], af1[8];
    #pragma unroll
    for (int k = 0; k < 8; ++k) {
        af0[k] = *(const short8*)(A0 + k*32);
        af1[k] = *(const short8*)(A1 + k*32);
    }
    f32x4 acc[2][2] = {{{0.f,0.f,0.f,0.f},{0.f,0.f,0.f,0.f}},
                       {{0.f,0.f,0.f,0.f},{0.f,0.f,0.f,0.f}}};
    #pragma unroll
    for (int nt = 0; nt < 2; ++nt) {
        #pragma unroll
        for (int k = 0; k < 8; ++k) {
            const short* bp = Wg2p + ((size_t)(k*4 + lg)*K_FEAT + f0 + nt*16 + lr)*8;
            short8 b = *(const short8*)bp;
            acc[0][nt] = __builtin_amdgcn_mfma_f32_16x16x32_bf16(af0[k], b, acc[0][nt], 0, 0, 0);
            acc[1][nt] = __builtin_amdgcn_mfma_f32_16x16x32_bf16(af1[k], b, acc[1][nt], 0, 0, 0);
        }
    }
    #pragma unroll
    for (int mt = 0; mt < 2; ++mt) {
        #pragma unroll
        for (int r = 0; r < 4; ++r) {
            int bb = mt*16 + lg*4 + r;
            size_t i0a = (size_t)bb*K_FEAT + f0 + lr;
            size_t i1a = i0a + 16;
            float v0, v1;
            if (FIRST) {
                v0 = 0.5f*(cxb[i0a] + acc[mt][0][r]);
                v1 = 0.5f*(cxb[i1a] + acc[mt][1][r]);
            } else {
                v0 = 0.5f*(y[i0a] + cxb[i0a] + acc[mt][0][r]);
                v1 = 0.5f*(y[i1a] + cxb[i1a] + acc[mt][1][r]);
            }
            float mx = fmaxf(v0, v1);
            #pragma unroll
            for (int m = 1; m <= 8; m <<= 1) mx = fmaxf(mx, __shfl_xor(mx, m));
            float d0 = v0 - mx, d1 = v1 - mx;
            float e10 = __expf(d0),      e11 = __expf(d1);
            float e30 = __expf(3.0f*d0), e31 = __expf(3.0f*d1);
            float s1 = e10 + e11, s3 = e30 + e31;
            #pragma unroll
            for (int m = 1; m <= 8; m <<= 1) { s1 += __shfl_xor(s1, m); s3 += __shfl_xor(s3, m); }
            float i1 = 1.0f/s1, i3 = 1.0f/s3;
            y[i0a] = v0; y[i1a] = v1;
            syb[i0a] = f2bf(e10*i1); syb[i1a] = f2bf(e11*i1);
            fyb[i0a] = f2bf(e30*i3); fyb[i1a] = f2bf(e31*i3);
        }
    }
}

// ---------------------------------------------------------------- convT MFMA: x = 0.9x + 0.1*conv_transpose(sy)
__global__ __launch_bounds__(256) void convT_mfma(const short* __restrict__ syb,
                                                  const short* __restrict__ KfragT,
                                                  float* __restrict__ x) {
    __shared__ __align__(16) short syt[25*41*32];   // 65600 B: [row][col][cy]
    int t = threadIdx.x;
    int tile = blockIdx.x;            // 0..7
    int b = blockIdx.y;
    int p0 = (tile >> 1) * 16, q0 = (tile & 1) * 32;
    for (int e = t; e < 1025; e += 256) {
        int row = e / 41, col = e - row*41;
        int gr = p0 - 9 + row, gc = q0 - 9 + col;
        short8 z = {0,0,0,0,0,0,0,0};
        short8 v0 = z, v1 = z, v2 = z, v3 = z;
        if (gr >= 0 && gr < 55 && gc >= 0 && gc < 55) {
            const short* sp = syb + ((size_t)b*K_P + gr*55 + gc) * 32;
            v0 = *(const short8*)(sp);
            v1 = *(const short8*)(sp + 8);
            v2 = *(const short8*)(sp + 16);
            v3 = *(const short8*)(sp + 24);
        }
        short* dp = syt + (size_t)e * 32;
        *(short8*)(dp)      = v0;
        *(short8*)(dp + 8)  = v1;
        *(short8*)(dp + 16) = v2;
        *(short8*)(dp + 24) = v3;
    }
    __syncthreads();
    int wid = t >> 6, l = t & 63, lr = l & 15, lg = l >> 4;
    f32x4 acc[4][2];
    #pragma unroll
    for (int r = 0; r < 4; ++r) { acc[r][0] = (f32x4){0,0,0,0}; acc[r][1] = (f32x4){0,0,0,0}; }
    const short* kfp = KfragT + (size_t)l * 8;
    for (int u = 0; u < 10; ++u) {
        #pragma unroll 5
        for (int v = 0; v < 10; ++v) {
            short8 a = *(const short8*)(kfp + (size_t)(u*10 + v)*512);
            #pragma unroll
            for (int r = 0; r < 4; ++r) {
                int rowlds = wid*4 + r + u;
                const short* bp = syt + ((size_t)(rowlds*41 + v + lr)*32 + lg*8);
                short8 b0 = *(const short8*)bp;
                short8 b1 = *(const short8*)(bp + 16*32);
                acc[r][0] = __builtin_amdgcn_mfma_f32_16x16x32_bf16(a, b0, acc[r][0], 0, 0, 0);
                acc[r][1] = __builtin_amdgcn_mfma_f32_16x16x32_bf16(a, b1, acc[r][1], 0, 0, 0);
            }
        }
    }
    if (lg == 0) {
        #pragma unroll
        for (int r = 0; r < 4; ++r) {
            int p = p0 + wid*4 + r;
            #pragma unroll
            for (int ct = 0; ct < 2; ++ct) {
                int q = q0 + ct*16 + lr;
                #pragma unroll
                for (int c = 0; c < 3; ++c) {
                    float* xp = x + (size_t)b*K_XN + c*4096 + p*64 + q;
                    *xp = 0.9f*(*xp) + 0.1f*acc[r][ct][c];
                }
            }
        }
    }
}

// ----------------------------------------------------------------
extern "C" void kernel_launch(void* const* d_in, const int* in_sizes, int n_in,
                              void* d_out, int out_size, void* d_ws, size_t ws_size,
                              hipStream_t stream) {
    const float* xin = (const float*)d_in[0];   // [32,3,64,64]
    const float* Kw  = (const float*)d_in[1];   // [32,3,10,10]
    const float* W   = (const float*)d_in[2];   // [256,96800]
    float* x = (float*)d_out;                   // x state lives in d_out

    float* ws     = (float*)d_ws;
    float* y      = ws;                         // 3,097,600 f   [b][p*32+cy]
    float* cxb    = y     + 3097600;            // 3,097,600 f   [b][p*32+cy]
    float* zpart  = cxb   + 3097600;            // 450,560 f
    float* zrow   = zpart + 450560;             // 256 f
    short* fyb    = (short*)(zrow + 256);       // 3,097,600 s   [b][p*32+cy]
    short* fzb    = fyb   + 3097600;            // 8,192 s
    short* Wbp    = fzb   + 8192;               // 24,780,800 s
    short* Wg2p   = Wbp   + 24780800;           // 24,780,800 s
    short* syb    = Wg2p  + 24780800;           // 3,097,600 s   [b][p*32+cy]
    short* KfragT = syb   + 3097600;            // 51,200 s
    short* Kfrag2 = KfragT+ 51200;              // 15,360 s

    hipMemcpyAsync(x, xin, (size_t)K_B*K_XN*sizeof(float), hipMemcpyDeviceToDevice, stream);
    hipMemsetAsync(zrow, 0, 256*sizeof(float), stream);
    prep_frags<<<33, 256, 0, stream>>>(Kw, KfragT, Kfrag2);
    w_perm1_t<<<dim3(12,256), 256, 0, stream>>>(W, Wbp, zrow);
    w_perm2_r<<<dim3(12,32), 256, 0, stream>>>(W, Wg2p);

    // step 0: fy = 1/32 uniform -> z = zrow/32 (exact), y starts at 0
    conv_first<<<512, 256, 0, stream>>>(x, cxb, Kfrag2);
    fzk_first<<<1, 256, 0, stream>>>(zrow, fzb);
    gemm2_sm<true><<<757, 256, 0, stream>>>(Wg2p, fzb, cxb, y, syb, fyb);
    convT_mfma<<<dim3(8,32), 256, 0, stream>>>(syb, KfragT, x);

    for (int s = 1; s < 30; ++s) {
        fused_A<<<732, 256, 0, stream>>>(x, cxb, Wbp, fyb, zpart, Kfrag2);
        fzk<<<32, 256, 0, stream>>>(zpart, fzb);
        gemm2_sm<false><<<757, 256, 0, stream>>>(Wg2p, fzb, cxb, y, syb, fyb);
        convT_mfma<<<dim3(8,32), 256, 0, stream>>>(syb, KfragT, x);
    }
}